// Round 19
// baseline (3152.671 us; speedup 1.0000x reference)
//
#include <hip/hip_runtime.h>
#include <cstddef>

typedef _Float16 f16x8 __attribute__((ext_vector_type(8)));
typedef _Float16 f16x4 __attribute__((ext_vector_type(4)));
typedef float f32x16 __attribute__((ext_vector_type(16)));
typedef unsigned short ushort_t;

#define NSEG 7168
#define NNODE 8192

enum { EP_NONE = 0, EP_BIAS = 1, EP_RAWP = 2, EP_NL1 = 3, EP_NL3 = 4 };

#define PHASE_BARRIER() do { asm volatile("s_waitcnt lgkmcnt(0)" ::: "memory"); \
                             __builtin_amdgcn_s_barrier(); } while (0)

#define RELU8(v) do { _Pragma("unroll") \
  for (int j_ = 0; j_ < 8; ++j_) v[j_] = v[j_] > (_Float16)0 ? v[j_] : (_Float16)0; } while (0)

// ---- prepack W[k][n] fp32 -> 32x32-fragment-native f16 into a pack of NTpack col-tiles
__global__ __launch_bounds__(256)
void prepack(const float* __restrict__ W, ushort_t* __restrict__ P,
             int koff, int kcnt, int Nsrc, int NTpack, int noff) {
  int idx = blockIdx.x * 256 + threadIdx.x;
  if (idx >= kcnt * Nsrc) return;
  int kl = idx / Nsrc, n = idx - kl * Nsrc + noff;
  _Float16 h = (_Float16)W[idx];
  int k = koff + kl;
  size_t o = ((((size_t)(k >> 4)) * NTpack + (n >> 5)) * 64 + ((k >> 3) & 1) * 32 + (n & 31)) * 8 + (k & 7);
  P[o] = __builtin_bit_cast(ushort_t, h);
}

// ---- cast fp32 -> f16 (flat mirror init) ---------------------------------
__global__ __launch_bounds__(256)
void cast16(const float* __restrict__ src, ushort_t* __restrict__ dst, int n) {
  int i = blockIdx.x * 256 + threadIdx.x;
  if (i < n) dst[i] = __builtin_bit_cast(ushort_t, (_Float16)src[i]);
}

// ---- v6[n] = 6 * sum_k e_b3[k] * n_w1[260+k][n] --------------------------
__global__ __launch_bounds__(256)
void v6k(const float* __restrict__ eb3, const float* __restrict__ nw1,
         float* __restrict__ v6) {
  int n = blockIdx.x * 256 + threadIdx.x;
  if (n >= 512) return;
  float a = 0.f;
  for (int k = 0; k < 512; ++k) a += eb3[k] * nw1[(size_t)(260 + k) * 512 + n];
  v6[n] = 6.f * a;
}

// ---- unified 64x128-tile MFMA GEMM, BK=128 phases, 4-deep B prefetch -----
// 256 thr / 4 waves, each wave 32 rows x 64 cols (2 col-tiles).
// LDS exactly 32 KiB; 5 blocks/CU target (160 KiB LDS, 96 VGPR <= 102).
template <int NCOLB, int EPI, int EDGE, int LNIN, int X1F16, int OUTF16>
__global__ __launch_bounds__(256, 5)
void gemmT(const void* __restrict__ X1v, int ld1, int nph1,
           const void* __restrict__ X2v, int ld2, int nph2,
           const ushort_t* __restrict__ Sm, const ushort_t* __restrict__ Tm,
           const ushort_t* __restrict__ P,
           const float* __restrict__ bias, const float* __restrict__ bias2,
           const int* __restrict__ action, const float* __restrict__ wact,
           const float* __restrict__ lnpart,
           const float* __restrict__ lng, const float* __restrict__ lnbn,
           void* __restrict__ Yv, float* __restrict__ Yres,
           float* __restrict__ Part, int m0base,
           ushort_t* __restrict__ YresH) {
  constexpr int N = NCOLB * 128;
  constexpr int NT = N / 32;
  const int u = threadIdx.x;
  // bijective XCD-chunk swizzle (m204)
  const int nwg = gridDim.x;
  const int qq = nwg >> 3, r8 = nwg & 7;
  const int xcd = blockIdx.x & 7, inx = blockIdx.x >> 3;
  const int logical = (xcd < r8 ? xcd * (qq + 1) : r8 * (qq + 1) + (xcd - r8) * qq) + inx;
  const int mY = (logical / NCOLB) * 64;
  const int cb = logical - (logical / NCOLB) * NCOLB;
  const int nB = cb * 128;
  const int lane = u & 63, w = u >> 6;
  const int wr = w >> 1, wc = w & 1;
  const int r31 = lane & 31, rt2 = lane >> 5;

  __shared__ ushort_t lA[16384];            // 2 x 8192 f16 = exactly 32 KiB

  // staging: thread (w, lane) stages row=lane, k = w*32..w*32+31 of the phase
  const int kcA = w * 2, kcB = w * 2 + 1;
  const int widx0 = (((rt2 * 8 + kcA) * 2 + 0) * 32 + (r31 ^ ((kcA & 3) << 3))) * 8;
  const int widx1 = (((rt2 * 8 + kcA) * 2 + 1) * 32 + (r31 ^ ((kcA & 3) << 3))) * 8;
  const int widx2 = (((rt2 * 8 + kcB) * 2 + 0) * 32 + (r31 ^ ((kcB & 3) << 3))) * 8;
  const int widx3 = (((rt2 * 8 + kcB) * 2 + 1) * 32 + (r31 ^ ((kcB & 3) << 3))) * 8;

  const ushort_t* sB = nullptr;
  const ushort_t* tB = nullptr;
  const float* x1f = nullptr;
  const ushort_t* x1h = nullptr;
  const ushort_t* x2h = nullptr;
  if (EDGE) {
    // per-thread edge decomposition (staging row = lane)
    int e = m0base + mY + lane;
    int b = e / 42, p = e - b * 42;
    int i = p / 6, tt = p - i * 6;
    int j = tt + (tt >= i ? 1 : 0);
    sB = Sm + (size_t)(b * 7 + i) * 1024 + w * 32;     // [7168][1024] S-half
    tB = Tm + (size_t)(b * 7 + j) * 1024 + w * 32;     // Tm = STb + 512
  } else {
    if (X1F16) x1h = (const ushort_t*)X1v + (size_t)(mY + lane) * ld1 + w * 32;
    else       x1f = (const float*)X1v + (size_t)(mY + lane) * ld1 + w * 32;
    if (nph2 > 0) x2h = (const ushort_t*)X2v + (size_t)(mY + lane) * ld2 + w * 32;
  }
  float mym = 0.f, myr = 0.f;
  if (LNIN) {
    const float* pp = lnpart + (size_t)(mY + lane) * 16;
    float S_ = 0.f, Q_ = 0.f;
    #pragma unroll
    for (int i = 0; i < 8; ++i) { S_ += pp[i]; Q_ += pp[8 + i]; }
    mym = S_ * (1.f / 512.f);
    myr = rsqrtf(Q_ * (1.f / 512.f) - mym * mym + 1e-5f);
  }

  f16x8 xc0, xc1, xc2, xc3;
  auto loadx = [&](int ph) {
    if (EDGE) {
      const ushort_t* sp = sB + ph * 128;
      const ushort_t* tp = tB + ph * 128;
      f16x8 s0 = *(const f16x8*)sp,        t0 = *(const f16x8*)tp;
      f16x8 s1 = *(const f16x8*)(sp + 8),  t1 = *(const f16x8*)(tp + 8);
      f16x8 s2 = *(const f16x8*)(sp + 16), t2 = *(const f16x8*)(tp + 16);
      f16x8 s3 = *(const f16x8*)(sp + 24), t3 = *(const f16x8*)(tp + 24);
      xc0 = s0 + t0; xc1 = s1 + t1; xc2 = s2 + t2; xc3 = s3 + t3;
      RELU8(xc0); RELU8(xc1); RELU8(xc2); RELU8(xc3);
    } else if (!X1F16 && ph < nph1) {
      const float* src = x1f + ph * 128;
      float4 l0 = *(const float4*)(src +  0), h0 = *(const float4*)(src +  4);
      float4 l1 = *(const float4*)(src +  8), h1 = *(const float4*)(src + 12);
      float4 l2 = *(const float4*)(src + 16), h2 = *(const float4*)(src + 20);
      float4 l3 = *(const float4*)(src + 24), h3 = *(const float4*)(src + 28);
#define CVT8(X, lo, hi) do { X[0]=(_Float16)lo.x; X[1]=(_Float16)lo.y; \
      X[2]=(_Float16)lo.z; X[3]=(_Float16)lo.w; X[4]=(_Float16)hi.x; \
      X[5]=(_Float16)hi.y; X[6]=(_Float16)hi.z; X[7]=(_Float16)hi.w; } while (0)
      CVT8(xc0, l0, h0); CVT8(xc1, l1, h1); CVT8(xc2, l2, h2); CVT8(xc3, l3, h3);
#undef CVT8
    } else {
      const ushort_t* src = (ph < nph1) ? x1h + ph * 128 : x2h + (ph - nph1) * 128;
      xc0 = *(const f16x8*)src;
      xc1 = *(const f16x8*)(src + 8);
      xc2 = *(const f16x8*)(src + 16);
      xc3 = *(const f16x8*)(src + 24);
      if (LNIN) {
        const int kb = ph * 128 + w * 32;
#define LN8(X, OFS) do { _Pragma("unroll") for (int j_ = 0; j_ < 8; ++j_) { \
        float xx = (float)X[j_]; \
        xx = fmaxf((xx - mym) * myr * lng[kb + (OFS) + j_] + lnbn[kb + (OFS) + j_], 0.f); \
        X[j_] = (_Float16)xx; } } while (0)
        LN8(xc0, 0); LN8(xc1, 8); LN8(xc2, 16); LN8(xc3, 24);
#undef LN8
      }
    }
  };
  auto cvtwrite = [&](int b) {
    const int base = b * 8192;
    *(f16x8*)&lA[base + widx0] = xc0;
    *(f16x8*)&lA[base + widx1] = xc1;
    *(f16x8*)&lA[base + widx2] = xc2;
    *(f16x8*)&lA[base + widx3] = xc3;
  };

  f32x16 acc0, acc1;
  #pragma unroll
  for (int q = 0; q < 16; ++q) { acc0[q] = 0.f; acc1[q] = 0.f; }

  const int nph = nph1 + nph2;
  const int ntb = (nB >> 5) + wc * 2;
  const int TOT = nph * 8;

#define LOADA(S, A_) do { \
    const int aofs_ = lbase + (((wr * 8 + (S)) * 2 + rt2) * 32 + (r31 ^ (((S) & 3) << 3))) * 8; \
    A_ = *(const f16x8*)&lA[aofs_]; } while (0)

#define LOADB(G_, H0, H1) do { \
    const ushort_t* bp_ = P + (((size_t)(G_) * NT + ntb) * 64 + lane) * 8; \
    H0 = *(const f16x8*)bp_; \
    H1 = *(const f16x8*)(bp_ + 512); } while (0)

#define MFMA2(AH, H0, H1) do { \
    acc0 = __builtin_amdgcn_mfma_f32_32x32x16_f16(AH, H0, acc0, 0, 0, 0); \
    acc1 = __builtin_amdgcn_mfma_f32_32x32x16_f16(AH, H1, acc1, 0, 0, 0); } while (0)

  // prologue: stage phase 0, issue phase-1 loads, prefetch B slots 0..3
  loadx(0);
  cvtwrite(0);
  if (nph > 1) loadx(1);
  PHASE_BARRIER();
  f16x8 b00, b01, b10, b11, b20, b21, b30, b31;
  LOADB(0, b00, b01);
  LOADB(1, b10, b11);
  LOADB(2, b20, b21);
  LOADB(3, b30, b31);

  #pragma unroll 1
  for (int ph = 0; ph < nph; ++ph) {
    if (ph + 1 < nph) {
      cvtwrite((ph + 1) & 1);
      if (ph + 2 < nph) loadx(ph + 2);
    }
    const int lbase = (ph & 1) * 8192;
    const int g0 = ph * 8;
    f16x8 ac, an;
    LOADA(0, ac);
#define STEP(S, BH, BL) do { \
    if ((S) < 7) LOADA((S) + 1, an); \
    f16x8 h0 = BH, h1 = BL; \
    if (g0 + (S) + 4 < TOT) LOADB(g0 + (S) + 4, BH, BL); \
    MFMA2(ac, h0, h1); \
    if ((S) < 7) ac = an; } while (0)
    STEP(0, b00, b01);
    STEP(1, b10, b11);
    STEP(2, b20, b21);
    STEP(3, b30, b31);
    STEP(4, b00, b01);
    STEP(5, b10, b11);
    STEP(6, b20, b21);
    STEP(7, b30, b31);
#undef STEP
    if (ph + 1 < nph) PHASE_BARRIER();
  }

  // ---- epilogue: C/D col = lane&31, row = (q&3) + 8*(q>>2) + 4*(lane>>5) --
  const int col0 = nB + wc * 64 + r31;
  float v[2][16];
  {
    float bc0 = (EPI == EP_NONE) ? 0.f : bias[col0];
    float bc1 = (EPI == EP_NONE) ? 0.f : bias[col0 + 32];
    #pragma unroll
    for (int q = 0; q < 16; ++q) {
      v[0][q] = acc0[q] + bc0;
      v[1][q] = acc1[q] + bc1;
    }
  }

  if (EPI == EP_NL1) {
    #pragma unroll
    for (int q = 0; q < 16; ++q) {
      int m = mY + wr * 32 + (q & 3) + 8 * (q >> 2) + 4 * rt2;
      if (m < NSEG) {
        v[0][q] += bias2[col0];
        v[1][q] += bias2[col0 + 32];
      }
      if (action != nullptr) {
        const float* wrp = wact + (size_t)(256 + action[m >> 3]) * 512;
        v[0][q] += wrp[col0];
        v[1][q] += wrp[col0 + 32];
      }
    }
    #pragma unroll
    for (int ct = 0; ct < 2; ++ct)
      #pragma unroll
      for (int q = 0; q < 16; ++q) v[ct][q] = fmaxf(v[ct][q], 0.f);
  }

  if (EPI == EP_RAWP) {
    float sv[16], qv[16];
    #pragma unroll
    for (int q = 0; q < 16; ++q) {
      sv[q] = v[0][q] + v[1][q];
      qv[q] = v[0][q] * v[0][q] + v[1][q] * v[1][q];
    }
    #pragma unroll
    for (int mm = 1; mm <= 16; mm <<= 1) {
      #pragma unroll
      for (int q = 0; q < 16; ++q) {
        sv[q] += __shfl_xor(sv[q], mm);
        qv[q] += __shfl_xor(qv[q], mm);
      }
    }
    if (r31 == 0) {
      #pragma unroll
      for (int q = 0; q < 16; ++q) {
        int m = mY + wr * 32 + (q & 3) + 8 * (q >> 2) + 4 * rt2;
        Part[(size_t)m * 16 + cb * 2 + wc] = sv[q];
        Part[(size_t)m * 16 + 8 + cb * 2 + wc] = qv[q];
      }
    }
  }

  #pragma unroll
  for (int ct = 0; ct < 2; ++ct) {
    #pragma unroll
    for (int q = 0; q < 16; ++q) {
      int m = mY + wr * 32 + (q & 3) + 8 * (q >> 2) + 4 * rt2;
      float z = v[ct][q];
      if (OUTF16)
        ((ushort_t*)Yv)[(size_t)m * N + col0 + ct * 32] =
            __builtin_bit_cast(ushort_t, (_Float16)z);
      else
        ((float*)Yv)[(size_t)m * N + col0 + ct * 32] = z;
      if (EPI == EP_NL3) {
        float t = Yres[(size_t)m * N + col0 + ct * 32] + z;
        Yres[(size_t)m * N + col0 + ct * 32] = t;
        YresH[(size_t)m * N + col0 + ct * 32] =
            __builtin_bit_cast(ushort_t, (_Float16)t);
      }
    }
  }
#undef LOADA
#undef LOADB
#undef MFMA2
}

// ---- LN(+relu) 6 H2 rows (f16) and sum per segment; stats from Part ------
__global__ __launch_bounds__(256)
void h2_sum_ln(const ushort_t* __restrict__ H2, const float* __restrict__ Part,
               const float* __restrict__ g, const float* __restrict__ bn,
               ushort_t* __restrict__ SS) {
  __shared__ float smu[12], srs[12];
  const int u = threadIdx.x;
  const int g2 = blockIdx.x * 2;
  if (u < 12) {
    const float* pp = Part + ((size_t)g2 * 6 + u) * 16;
    float S = 0.f, Q = 0.f;
    #pragma unroll
    for (int i = 0; i < 8; ++i) { S += pp[i]; Q += pp[8 + i]; }
    float m = S * (1.f / 512.f);
    smu[u] = m;
    srs[u] = rsqrtf(Q * (1.f / 512.f) - m * m + 1e-5f);
  }
  __syncthreads();
  const int ln = g2 + (u >> 7);
  const int lloc = (u >> 7) * 6;
  const int c4 = (u & 127) * 4;
  float4 gv = *(const float4*)(g + c4);
  float4 bv = *(const float4*)(bn + c4);
  float a0 = 0.f, a1 = 0.f, a2 = 0.f, a3 = 0.f;
  #pragma unroll
  for (int r = 0; r < 6; ++r) {
    int row = ln * 6 + r;
    f16x4 y = *(const f16x4*)(H2 + (size_t)row * 512 + c4);
    float m = smu[lloc + r], rs = srs[lloc + r];
    a0 += fmaxf(((float)y[0] - m) * rs * gv.x + bv.x, 0.f);
    a1 += fmaxf(((float)y[1] - m) * rs * gv.y + bv.y, 0.f);
    a2 += fmaxf(((float)y[2] - m) * rs * gv.z + bv.z, 0.f);
    a3 += fmaxf(((float)y[3] - m) * rs * gv.w + bv.w, 0.f);
  }
  f16x4 o;
  o[0] = (_Float16)a0; o[1] = (_Float16)a1; o[2] = (_Float16)a2; o[3] = (_Float16)a3;
  *(f16x4*)(SS + (size_t)ln * 512 + c4) = o;
}

// ---- launcher ------------------------------------------------------------
extern "C" void kernel_launch(void* const* d_in, const int* in_sizes, int n_in,
                              void* d_out, int out_size, void* d_ws, size_t ws_size,
                              hipStream_t stream) {
  (void)in_sizes; (void)n_in; (void)out_size;
  const float* states = (const float*)d_in[0];
  const int* action = (const int*)d_in[1];
  const float* e_w1 = (const float*)d_in[2];
  const float* e_b1 = (const float*)d_in[3];
  const float* e_w2 = (const float*)d_in[4];
  const float* e_b2 = (const float*)d_in[5];
  const float* e_g = (const float*)d_in[6];
  const float* e_bn = (const float*)d_in[7];
  const float* e_w3 = (const float*)d_in[8];
  const float* e_b3 = (const float*)d_in[9];
  const float* n_w1 = (const float*)d_in[10];
  const float* n_b1 = (const float*)d_in[11];
  const float* n_w2 = (const float*)d_in[12];
  const float* n_b2 = (const float*)d_in[13];
  const float* n_g = (const float*)d_in[14];
  const float* n_bn = (const float*)d_in[15];
  const float* n_w3 = (const float*)d_in[16];
  const float* n_b3 = (const float*)d_in[17];

  float* flat = (float*)d_out;                  // [8192][256] fp32 (output)
  float* fp = (float*)d_ws;
  float* Mbuf = fp;  fp += 262144;              // [512][512] fp32
  float* v6 = fp;    fp += 512;
  float* b1ext = fp; fp += 1024;                // [e_b1 | 0]
  float* PartE = fp; fp += 688128;              // [43008][16]
  float* PartN = fp; fp += 131072;              // [8192][16]
  ushort_t* us = (ushort_t*)fp;
  ushort_t* node = us; us += 2097152;           // [8192][256] f16
  ushort_t* flatH = us; us += 2097152;          // [8192][256] f16 mirror of flat
  ushort_t* SS = us;   us += 4194304;           // [8192][512] f16 (tail zeros)
  ushort_t* G = us;    us += 4194304;           // [8192][512] f16
  ushort_t* G2 = us;   us += 4194304;           // [8192][512] f16
  ushort_t* STb = us;  us += 7340032;           // [7168][1024] f16  [S|T]
  ushort_t* PeST = us; us += 524288;            // K512 N1024
  ushort_t* PeW2 = us; us += 262144;
  ushort_t* Ptmp = us; us += 262144;
  ushort_t* PnW1M = us; us += 393216;
  ushort_t* PnW2 = us;  us += 262144;
  ushort_t* PnW3 = us;  us += 131072;
  ushort_t* H2 = us;                            // [43008/nc][512] f16

  const size_t fixedB = (size_t)((char*)H2 - (char*)d_ws);
  int nc = 32;
  for (int cand = 1; cand <= 32; cand <<= 1)
    if (fixedB + (43008ull / cand) * 512ull * 2ull <= ws_size) { nc = cand; break; }
  const int spc = 1024 / nc;
  const int epc = spc * 42;

  // ---- one-time prep ----
  hipMemsetAsync(PeST, 0, 524288 * 2, stream);
  prepack<<<1024, 256, 0, stream>>>(e_w1, PeST, 0, 512, 512, 32, 0);
  prepack<<<512, 256, 0, stream>>>(e_w1 + 262144, PeST, 0, 256, 512, 32, 512);
  prepack<<<1024, 256, 0, stream>>>(e_w2, PeW2, 0, 512, 512, 16, 0);
  prepack<<<1024, 256, 0, stream>>>(n_w1 + 133120, Ptmp, 0, 512, 512, 16, 0);
  prepack<<<512, 256, 0, stream>>>(n_w1, PnW1M, 0, 256, 512, 16, 0);
  prepack<<<1024, 256, 0, stream>>>(n_w2, PnW2, 0, 512, 512, 16, 0);
  prepack<<<512, 256, 0, stream>>>(n_w3, PnW3, 0, 512, 256, 8, 0);
  hipMemcpyAsync(b1ext, e_b1, 512 * 4, hipMemcpyDeviceToDevice, stream);
  hipMemsetAsync(b1ext + 512, 0, 512 * 4, stream);
  // M = e_w3 @ n_w1g (512x512, K=512), fp32 out -> repack
  gemmT<4, EP_NONE, 0, 0, 0, 0><<<32, 256, 0, stream>>>(
      e_w3, 512, 4, nullptr, 0, 0, nullptr, nullptr, Ptmp, nullptr, nullptr,
      nullptr, nullptr, nullptr, nullptr, nullptr, Mbuf, nullptr, nullptr, 0, nullptr);
  prepack<<<1024, 256, 0, stream>>>(Mbuf, PnW1M, 256, 512, 512, 16, 0);
  v6k<<<2, 256, 0, stream>>>(e_b3, n_w1, v6);
  hipMemsetAsync(SS + (size_t)NSEG * 512, 0, (size_t)(NNODE - NSEG) * 512 * 2, stream);
  hipMemcpyAsync(flat, states, (size_t)NNODE * 256 * 4, hipMemcpyDeviceToDevice, stream);
  cast16<<<8192, 256, 0, stream>>>(states, flatH, NNODE * 256);

  for (int round = 0; round < 8; ++round) {
    // [S|T] = [flatH|node] @ PeST + [b1|0]  (7168 rows, N=1024, f16 out)
    if (round == 0)
      gemmT<8, EP_BIAS, 0, 0, 1, 1><<<896, 256, 0, stream>>>(
          flatH, 256, 2, nullptr, 0, 0, nullptr, nullptr, PeST, b1ext, nullptr,
          nullptr, nullptr, nullptr, nullptr, nullptr, STb, nullptr, nullptr, 0, nullptr);
    else
      gemmT<8, EP_BIAS, 0, 0, 1, 1><<<896, 256, 0, stream>>>(
          flatH, 256, 2, node, 256, 2, nullptr, nullptr, PeST, b1ext, nullptr,
          nullptr, nullptr, nullptr, nullptr, nullptr, STb, nullptr, nullptr, 0, nullptr);
    // edge layer 2 (gather S[row]+T[col], relu) raw f16 + fp32 partials; LN+sum6
    for (int ch = 0; ch < nc; ++ch) {
      gemmT<4, EP_RAWP, 1, 0, 0, 1><<<(epc / 64) * 4, 256, 0, stream>>>(
          nullptr, 0, 4, nullptr, 0, 0, STb, STb + 512, PeW2, e_b2, nullptr,
          nullptr, nullptr, nullptr, nullptr, nullptr,
          H2, nullptr, PartE, ch * epc, nullptr);
      h2_sum_ln<<<(spc * 7) / 2, 256, 0, stream>>>(
          H2, PartE, e_g, e_bn, SS + (size_t)ch * spc * 7 * 512);
    }
    // node L1 (agg GEMM folded): relu(flatH@W1f + SS@M + b1 + [m<7168]v6 + av) -> G
    gemmT<4, EP_NL1, 0, 0, 1, 1><<<512, 256, 0, stream>>>(
        flatH, 256, 2, SS, 512, 4, nullptr, nullptr, PnW1M, n_b1, v6,
        (round == 0) ? action : nullptr, n_w1,
        nullptr, nullptr, nullptr, G, nullptr, nullptr, 0, nullptr);
    // node L2 raw + partials: G -> G2
    gemmT<4, EP_RAWP, 0, 0, 1, 1><<<512, 256, 0, stream>>>(
        G, 512, 4, nullptr, 0, 0, nullptr, nullptr, PnW2, n_b2, nullptr,
        nullptr, nullptr, nullptr, nullptr, nullptr, G2, nullptr, PartN, 0, nullptr);
    // node L3 (+LN on staging, stats from PartN) + residual: G2 -> node, flat+=, flatH=
    gemmT<2, EP_NL3, 0, 1, 1, 1><<<256, 256, 0, stream>>>(
        G2, 512, 4, nullptr, 0, 0, nullptr, nullptr, PnW3, n_b3, nullptr,
        nullptr, nullptr, PartN, n_g, n_bn, node, flat, nullptr, 0, flatH);
  }
}

// Round 20
// 1281.915 us; speedup vs baseline: 2.4593x; 2.4593x over previous
//
#include <hip/hip_runtime.h>
#include <cstddef>

typedef _Float16 f16x8 __attribute__((ext_vector_type(8)));
typedef _Float16 f16x4 __attribute__((ext_vector_type(4)));
typedef float f32x16 __attribute__((ext_vector_type(16)));
typedef unsigned short ushort_t;

#define NSEG 7168
#define NNODE 8192

enum { EP_NONE = 0, EP_BIAS = 1, EP_RAWP = 2, EP_NL1 = 3, EP_NL3 = 4 };

#define PHASE_BARRIER() do { asm volatile("s_waitcnt lgkmcnt(0)" ::: "memory"); \
                             __builtin_amdgcn_s_barrier(); } while (0)

#define RELU8(v) do { _Pragma("unroll") \
  for (int j_ = 0; j_ < 8; ++j_) v[j_] = v[j_] > (_Float16)0 ? v[j_] : (_Float16)0; } while (0)

// ---- prepack W[k][n] fp32 -> 32x32-fragment-native f16 into a pack of NTpack col-tiles
__global__ __launch_bounds__(256)
void prepack(const float* __restrict__ W, ushort_t* __restrict__ P,
             int koff, int kcnt, int Nsrc, int NTpack, int noff) {
  int idx = blockIdx.x * 256 + threadIdx.x;
  if (idx >= kcnt * Nsrc) return;
  int kl = idx / Nsrc, n = idx - kl * Nsrc + noff;
  _Float16 h = (_Float16)W[idx];
  int k = koff + kl;
  size_t o = ((((size_t)(k >> 4)) * NTpack + (n >> 5)) * 64 + ((k >> 3) & 1) * 32 + (n & 31)) * 8 + (k & 7);
  P[o] = __builtin_bit_cast(ushort_t, h);
}

// ---- v6[n] = 6 * sum_k e_b3[k] * n_w1[260+k][n] --------------------------
__global__ __launch_bounds__(256)
void v6k(const float* __restrict__ eb3, const float* __restrict__ nw1,
         float* __restrict__ v6) {
  int n = blockIdx.x * 256 + threadIdx.x;
  if (n >= 512) return;
  float a = 0.f;
  for (int k = 0; k < 512; ++k) a += eb3[k] * nw1[(size_t)(260 + k) * 512 + n];
  v6[n] = 6.f * a;
}

// ---- unified 64x128-tile MFMA GEMM, BK=128 phases, 4-deep B prefetch -----
// 256 thr / 4 waves, each wave 32 rows x 64 cols (2 col-tiles).
// LDS exactly 32 KiB (no aux arrays).
template <int NCOLB, int EPI, int EDGE, int LNIN, int X1F16, int OUTF16>
__global__ __launch_bounds__(256, 4)
void gemmT(const void* __restrict__ X1v, int ld1, int nph1,
           const void* __restrict__ X2v, int ld2, int nph2,
           const ushort_t* __restrict__ Sm, const ushort_t* __restrict__ Tm,
           const ushort_t* __restrict__ P,
           const float* __restrict__ bias, const float* __restrict__ bias2,
           const int* __restrict__ action, const float* __restrict__ wact,
           const float* __restrict__ lnpart,
           const float* __restrict__ lng, const float* __restrict__ lnbn,
           void* __restrict__ Yv, float* __restrict__ Yres,
           float* __restrict__ Part, int m0base) {
  constexpr int N = NCOLB * 128;
  constexpr int NT = N / 32;
  const int u = threadIdx.x;
  // bijective XCD-chunk swizzle (m204)
  const int nwg = gridDim.x;
  const int qq = nwg >> 3, r8 = nwg & 7;
  const int xcd = blockIdx.x & 7, inx = blockIdx.x >> 3;
  const int logical = (xcd < r8 ? xcd * (qq + 1) : r8 * (qq + 1) + (xcd - r8) * qq) + inx;
  const int mY = (logical / NCOLB) * 64;
  const int cb = logical - (logical / NCOLB) * NCOLB;
  const int nB = cb * 128;
  const int lane = u & 63, w = u >> 6;
  const int wr = w >> 1, wc = w & 1;
  const int r31 = lane & 31, rt2 = lane >> 5;

  __shared__ ushort_t lA[16384];            // 2 x 8192 f16 = exactly 32 KiB

  // staging: thread (w, lane) stages row=lane, k = w*32..w*32+31 of the phase
  const int kcA = w * 2, kcB = w * 2 + 1;
  const int widx0 = (((rt2 * 8 + kcA) * 2 + 0) * 32 + (r31 ^ ((kcA & 3) << 3))) * 8;
  const int widx1 = (((rt2 * 8 + kcA) * 2 + 1) * 32 + (r31 ^ ((kcA & 3) << 3))) * 8;
  const int widx2 = (((rt2 * 8 + kcB) * 2 + 0) * 32 + (r31 ^ ((kcB & 3) << 3))) * 8;
  const int widx3 = (((rt2 * 8 + kcB) * 2 + 1) * 32 + (r31 ^ ((kcB & 3) << 3))) * 8;

  const ushort_t* sB = nullptr;
  const ushort_t* tB = nullptr;
  const float* x1f = nullptr;
  const ushort_t* x1h = nullptr;
  const ushort_t* x2h = nullptr;
  if (EDGE) {
    // per-thread edge decomposition (staging row = lane)
    int e = m0base + mY + lane;
    int b = e / 42, p = e - b * 42;
    int i = p / 6, tt = p - i * 6;
    int j = tt + (tt >= i ? 1 : 0);
    sB = Sm + (size_t)(b * 7 + i) * 1024 + w * 32;     // [7168][1024] S-half
    tB = Tm + (size_t)(b * 7 + j) * 1024 + w * 32;     // Tm = STb + 512
  } else {
    if (X1F16) x1h = (const ushort_t*)X1v + (size_t)(mY + lane) * ld1 + w * 32;
    else       x1f = (const float*)X1v + (size_t)(mY + lane) * ld1 + w * 32;
    if (nph2 > 0) x2h = (const ushort_t*)X2v + (size_t)(mY + lane) * ld2 + w * 32;
  }
  float mym = 0.f, myr = 0.f;
  if (LNIN) {
    const float* pp = lnpart + (size_t)(mY + lane) * 16;
    float S_ = 0.f, Q_ = 0.f;
    #pragma unroll
    for (int i = 0; i < 8; ++i) { S_ += pp[i]; Q_ += pp[8 + i]; }
    mym = S_ * (1.f / 512.f);
    myr = rsqrtf(Q_ * (1.f / 512.f) - mym * mym + 1e-5f);
  }

  f16x8 xc0, xc1, xc2, xc3;
  auto loadx = [&](int ph) {
    if (EDGE) {
      const ushort_t* sp = sB + ph * 128;
      const ushort_t* tp = tB + ph * 128;
      f16x8 s0 = *(const f16x8*)sp,        t0 = *(const f16x8*)tp;
      f16x8 s1 = *(const f16x8*)(sp + 8),  t1 = *(const f16x8*)(tp + 8);
      f16x8 s2 = *(const f16x8*)(sp + 16), t2 = *(const f16x8*)(tp + 16);
      f16x8 s3 = *(const f16x8*)(sp + 24), t3 = *(const f16x8*)(tp + 24);
      xc0 = s0 + t0; xc1 = s1 + t1; xc2 = s2 + t2; xc3 = s3 + t3;
      RELU8(xc0); RELU8(xc1); RELU8(xc2); RELU8(xc3);
    } else if (!X1F16 && ph < nph1) {
      const float* src = x1f + ph * 128;
      float4 l0 = *(const float4*)(src +  0), h0 = *(const float4*)(src +  4);
      float4 l1 = *(const float4*)(src +  8), h1 = *(const float4*)(src + 12);
      float4 l2 = *(const float4*)(src + 16), h2 = *(const float4*)(src + 20);
      float4 l3 = *(const float4*)(src + 24), h3 = *(const float4*)(src + 28);
#define CVT8(X, lo, hi) do { X[0]=(_Float16)lo.x; X[1]=(_Float16)lo.y; \
      X[2]=(_Float16)lo.z; X[3]=(_Float16)lo.w; X[4]=(_Float16)hi.x; \
      X[5]=(_Float16)hi.y; X[6]=(_Float16)hi.z; X[7]=(_Float16)hi.w; } while (0)
      CVT8(xc0, l0, h0); CVT8(xc1, l1, h1); CVT8(xc2, l2, h2); CVT8(xc3, l3, h3);
#undef CVT8
    } else {
      const ushort_t* src = (ph < nph1) ? x1h + ph * 128 : x2h + (ph - nph1) * 128;
      xc0 = *(const f16x8*)src;
      xc1 = *(const f16x8*)(src + 8);
      xc2 = *(const f16x8*)(src + 16);
      xc3 = *(const f16x8*)(src + 24);
      if (LNIN) {
        const int kb = ph * 128 + w * 32;
#define LN8(X, OFS) do { _Pragma("unroll") for (int j_ = 0; j_ < 8; ++j_) { \
        float xx = (float)X[j_]; \
        xx = fmaxf((xx - mym) * myr * lng[kb + (OFS) + j_] + lnbn[kb + (OFS) + j_], 0.f); \
        X[j_] = (_Float16)xx; } } while (0)
        LN8(xc0, 0); LN8(xc1, 8); LN8(xc2, 16); LN8(xc3, 24);
#undef LN8
      }
    }
  };
  auto cvtwrite = [&](int b) {
    const int base = b * 8192;
    *(f16x8*)&lA[base + widx0] = xc0;
    *(f16x8*)&lA[base + widx1] = xc1;
    *(f16x8*)&lA[base + widx2] = xc2;
    *(f16x8*)&lA[base + widx3] = xc3;
  };

  f32x16 acc0, acc1;
  #pragma unroll
  for (int q = 0; q < 16; ++q) { acc0[q] = 0.f; acc1[q] = 0.f; }

  const int nph = nph1 + nph2;
  const int ntb = (nB >> 5) + wc * 2;
  const int TOT = nph * 8;

#define LOADA(S, A_) do { \
    const int aofs_ = lbase + (((wr * 8 + (S)) * 2 + rt2) * 32 + (r31 ^ (((S) & 3) << 3))) * 8; \
    A_ = *(const f16x8*)&lA[aofs_]; } while (0)

#define LOADB(G_, H0, H1) do { \
    const ushort_t* bp_ = P + (((size_t)(G_) * NT + ntb) * 64 + lane) * 8; \
    H0 = *(const f16x8*)bp_; \
    H1 = *(const f16x8*)(bp_ + 512); } while (0)

#define MFMA2(AH, H0, H1) do { \
    acc0 = __builtin_amdgcn_mfma_f32_32x32x16_f16(AH, H0, acc0, 0, 0, 0); \
    acc1 = __builtin_amdgcn_mfma_f32_32x32x16_f16(AH, H1, acc1, 0, 0, 0); } while (0)

  // prologue: stage phase 0, issue phase-1 loads, prefetch B slots 0..3
  loadx(0);
  cvtwrite(0);
  if (nph > 1) loadx(1);
  PHASE_BARRIER();
  f16x8 b00, b01, b10, b11, b20, b21, b30, b31;
  LOADB(0, b00, b01);
  LOADB(1, b10, b11);
  LOADB(2, b20, b21);
  LOADB(3, b30, b31);

  #pragma unroll 1
  for (int ph = 0; ph < nph; ++ph) {
    if (ph + 1 < nph) {
      cvtwrite((ph + 1) & 1);
      if (ph + 2 < nph) loadx(ph + 2);
    }
    const int lbase = (ph & 1) * 8192;
    const int g0 = ph * 8;
    f16x8 ac, an;
    LOADA(0, ac);
#define STEP(S, BH, BL) do { \
    if ((S) < 7) LOADA((S) + 1, an); \
    f16x8 h0 = BH, h1 = BL; \
    if (g0 + (S) + 4 < TOT) LOADB(g0 + (S) + 4, BH, BL); \
    MFMA2(ac, h0, h1); \
    if ((S) < 7) ac = an; } while (0)
    STEP(0, b00, b01);
    STEP(1, b10, b11);
    STEP(2, b20, b21);
    STEP(3, b30, b31);
    STEP(4, b00, b01);
    STEP(5, b10, b11);
    STEP(6, b20, b21);
    STEP(7, b30, b31);
#undef STEP
    if (ph + 1 < nph) PHASE_BARRIER();
  }

  // ---- epilogue: C/D col = lane&31, row = (q&3) + 8*(q>>2) + 4*(lane>>5) --
  const int col0 = nB + wc * 64 + r31;
  float v[2][16];
  {
    float bc0 = (EPI == EP_NONE) ? 0.f : bias[col0];
    float bc1 = (EPI == EP_NONE) ? 0.f : bias[col0 + 32];
    #pragma unroll
    for (int q = 0; q < 16; ++q) {
      v[0][q] = acc0[q] + bc0;
      v[1][q] = acc1[q] + bc1;
    }
  }

  if (EPI == EP_NL1) {
    #pragma unroll
    for (int q = 0; q < 16; ++q) {
      int m = mY + wr * 32 + (q & 3) + 8 * (q >> 2) + 4 * rt2;
      if (m < NSEG) {
        v[0][q] += bias2[col0];
        v[1][q] += bias2[col0 + 32];
      }
      if (action != nullptr) {
        const float* wrp = wact + (size_t)(256 + action[m >> 3]) * 512;
        v[0][q] += wrp[col0];
        v[1][q] += wrp[col0 + 32];
      }
    }
    #pragma unroll
    for (int ct = 0; ct < 2; ++ct)
      #pragma unroll
      for (int q = 0; q < 16; ++q) v[ct][q] = fmaxf(v[ct][q], 0.f);
  }

  if (EPI == EP_RAWP) {
    float sv[16], qv[16];
    #pragma unroll
    for (int q = 0; q < 16; ++q) {
      sv[q] = v[0][q] + v[1][q];
      qv[q] = v[0][q] * v[0][q] + v[1][q] * v[1][q];
    }
    #pragma unroll
    for (int mm = 1; mm <= 16; mm <<= 1) {
      #pragma unroll
      for (int q = 0; q < 16; ++q) {
        sv[q] += __shfl_xor(sv[q], mm);
        qv[q] += __shfl_xor(qv[q], mm);
      }
    }
    if (r31 == 0) {
      #pragma unroll
      for (int q = 0; q < 16; ++q) {
        int m = mY + wr * 32 + (q & 3) + 8 * (q >> 2) + 4 * rt2;
        Part[(size_t)m * 16 + cb * 2 + wc] = sv[q];
        Part[(size_t)m * 16 + 8 + cb * 2 + wc] = qv[q];
      }
    }
  }

  #pragma unroll
  for (int ct = 0; ct < 2; ++ct) {
    #pragma unroll
    for (int q = 0; q < 16; ++q) {
      int m = mY + wr * 32 + (q & 3) + 8 * (q >> 2) + 4 * rt2;
      float z = v[ct][q];
      if (OUTF16)
        ((ushort_t*)Yv)[(size_t)m * N + col0 + ct * 32] =
            __builtin_bit_cast(ushort_t, (_Float16)z);
      else
        ((float*)Yv)[(size_t)m * N + col0 + ct * 32] = z;
      if (EPI == EP_NL3) Yres[(size_t)m * N + col0 + ct * 32] += z;
    }
  }
#undef LOADA
#undef LOADB
#undef MFMA2
}

// ---- LN(+relu) 6 H2 rows (f16) and sum per segment; stats from Part ------
__global__ __launch_bounds__(256)
void h2_sum_ln(const ushort_t* __restrict__ H2, const float* __restrict__ Part,
               const float* __restrict__ g, const float* __restrict__ bn,
               ushort_t* __restrict__ SS) {
  __shared__ float smu[12], srs[12];
  const int u = threadIdx.x;
  const int g2 = blockIdx.x * 2;
  if (u < 12) {
    const float* pp = Part + ((size_t)g2 * 6 + u) * 16;
    float S = 0.f, Q = 0.f;
    #pragma unroll
    for (int i = 0; i < 8; ++i) { S += pp[i]; Q += pp[8 + i]; }
    float m = S * (1.f / 512.f);
    smu[u] = m;
    srs[u] = rsqrtf(Q * (1.f / 512.f) - m * m + 1e-5f);
  }
  __syncthreads();
  const int ln = g2 + (u >> 7);
  const int lloc = (u >> 7) * 6;
  const int c4 = (u & 127) * 4;
  float4 gv = *(const float4*)(g + c4);
  float4 bv = *(const float4*)(bn + c4);
  float a0 = 0.f, a1 = 0.f, a2 = 0.f, a3 = 0.f;
  #pragma unroll
  for (int r = 0; r < 6; ++r) {
    int row = ln * 6 + r;
    f16x4 y = *(const f16x4*)(H2 + (size_t)row * 512 + c4);
    float m = smu[lloc + r], rs = srs[lloc + r];
    a0 += fmaxf(((float)y[0] - m) * rs * gv.x + bv.x, 0.f);
    a1 += fmaxf(((float)y[1] - m) * rs * gv.y + bv.y, 0.f);
    a2 += fmaxf(((float)y[2] - m) * rs * gv.z + bv.z, 0.f);
    a3 += fmaxf(((float)y[3] - m) * rs * gv.w + bv.w, 0.f);
  }
  f16x4 o;
  o[0] = (_Float16)a0; o[1] = (_Float16)a1; o[2] = (_Float16)a2; o[3] = (_Float16)a3;
  *(f16x4*)(SS + (size_t)ln * 512 + c4) = o;
}

// ---- launcher ------------------------------------------------------------
extern "C" void kernel_launch(void* const* d_in, const int* in_sizes, int n_in,
                              void* d_out, int out_size, void* d_ws, size_t ws_size,
                              hipStream_t stream) {
  (void)in_sizes; (void)n_in; (void)out_size;
  const float* states = (const float*)d_in[0];
  const int* action = (const int*)d_in[1];
  const float* e_w1 = (const float*)d_in[2];
  const float* e_b1 = (const float*)d_in[3];
  const float* e_w2 = (const float*)d_in[4];
  const float* e_b2 = (const float*)d_in[5];
  const float* e_g = (const float*)d_in[6];
  const float* e_bn = (const float*)d_in[7];
  const float* e_w3 = (const float*)d_in[8];
  const float* e_b3 = (const float*)d_in[9];
  const float* n_w1 = (const float*)d_in[10];
  const float* n_b1 = (const float*)d_in[11];
  const float* n_w2 = (const float*)d_in[12];
  const float* n_b2 = (const float*)d_in[13];
  const float* n_g = (const float*)d_in[14];
  const float* n_bn = (const float*)d_in[15];
  const float* n_w3 = (const float*)d_in[16];
  const float* n_b3 = (const float*)d_in[17];

  float* flat = (float*)d_out;                  // [8192][256] fp32 (output)
  float* fp = (float*)d_ws;
  float* Mbuf = fp;  fp += 262144;              // [512][512] fp32
  float* v6 = fp;    fp += 512;
  float* b1ext = fp; fp += 1024;                // [e_b1 | 0]
  float* PartE = fp; fp += 688128;              // [43008][16]
  float* PartN = fp; fp += 131072;              // [8192][16]
  ushort_t* us = (ushort_t*)fp;
  ushort_t* node = us; us += 2097152;           // [8192][256] f16
  ushort_t* SS = us;   us += 4194304;           // [8192][512] f16 (tail zeros)
  ushort_t* G = us;    us += 4194304;           // [8192][512] f16
  ushort_t* G2 = us;   us += 4194304;           // [8192][512] f16
  ushort_t* STb = us;  us += 7340032;           // [7168][1024] f16  [S|T]
  ushort_t* PeST = us; us += 524288;            // K512 N1024
  ushort_t* PeW2 = us; us += 262144;
  ushort_t* Ptmp = us; us += 262144;
  ushort_t* PnW1M = us; us += 393216;
  ushort_t* PnW2 = us;  us += 262144;
  ushort_t* PnW3 = us;  us += 131072;
  ushort_t* H2 = us;                            // [43008/nc][512] f16

  const size_t fixedB = (size_t)((char*)H2 - (char*)d_ws);
  int nc = 32;
  for (int cand = 1; cand <= 32; cand <<= 1)
    if (fixedB + (43008ull / cand) * 512ull * 2ull <= ws_size) { nc = cand; break; }
  const int spc = 1024 / nc;
  const int epc = spc * 42;

  // ---- one-time prep ----
  hipMemsetAsync(PeST, 0, 524288 * 2, stream);
  prepack<<<1024, 256, 0, stream>>>(e_w1, PeST, 0, 512, 512, 32, 0);
  prepack<<<512, 256, 0, stream>>>(e_w1 + 262144, PeST, 0, 256, 512, 32, 512);
  prepack<<<1024, 256, 0, stream>>>(e_w2, PeW2, 0, 512, 512, 16, 0);
  prepack<<<1024, 256, 0, stream>>>(n_w1 + 133120, Ptmp, 0, 512, 512, 16, 0);
  prepack<<<512, 256, 0, stream>>>(n_w1, PnW1M, 0, 256, 512, 16, 0);
  prepack<<<1024, 256, 0, stream>>>(n_w2, PnW2, 0, 512, 512, 16, 0);
  prepack<<<512, 256, 0, stream>>>(n_w3, PnW3, 0, 512, 256, 8, 0);
  hipMemcpyAsync(b1ext, e_b1, 512 * 4, hipMemcpyDeviceToDevice, stream);
  hipMemsetAsync(b1ext + 512, 0, 512 * 4, stream);
  // M = e_w3 @ n_w1g (512x512, K=512), fp32 out -> repack
  gemmT<4, EP_NONE, 0, 0, 0, 0><<<32, 256, 0, stream>>>(
      e_w3, 512, 4, nullptr, 0, 0, nullptr, nullptr, Ptmp, nullptr, nullptr,
      nullptr, nullptr, nullptr, nullptr, nullptr, Mbuf, nullptr, nullptr, 0);
  prepack<<<1024, 256, 0, stream>>>(Mbuf, PnW1M, 256, 512, 512, 16, 0);
  v6k<<<2, 256, 0, stream>>>(e_b3, n_w1, v6);
  hipMemsetAsync(SS + (size_t)NSEG * 512, 0, (size_t)(NNODE - NSEG) * 512 * 2, stream);
  hipMemcpyAsync(flat, states, (size_t)NNODE * 256 * 4, hipMemcpyDeviceToDevice, stream);

  for (int round = 0; round < 8; ++round) {
    // [S|T] = [flat|node] @ PeST + [b1|0]  (7168 rows, N=1024, f16 out)
    if (round == 0)
      gemmT<8, EP_BIAS, 0, 0, 0, 1><<<896, 256, 0, stream>>>(
          flat, 256, 2, nullptr, 0, 0, nullptr, nullptr, PeST, b1ext, nullptr,
          nullptr, nullptr, nullptr, nullptr, nullptr, STb, nullptr, nullptr, 0);
    else
      gemmT<8, EP_BIAS, 0, 0, 0, 1><<<896, 256, 0, stream>>>(
          flat, 256, 2, node, 256, 2, nullptr, nullptr, PeST, b1ext, nullptr,
          nullptr, nullptr, nullptr, nullptr, nullptr, STb, nullptr, nullptr, 0);
    // edge layer 2 (gather S[row]+T[col], relu) raw f16 + fp32 partials; LN+sum6
    for (int ch = 0; ch < nc; ++ch) {
      gemmT<4, EP_RAWP, 1, 0, 0, 1><<<(epc / 64) * 4, 256, 0, stream>>>(
          nullptr, 0, 4, nullptr, 0, 0, STb, STb + 512, PeW2, e_b2, nullptr,
          nullptr, nullptr, nullptr, nullptr, nullptr,
          H2, nullptr, PartE, ch * epc);
      h2_sum_ln<<<(spc * 7) / 2, 256, 0, stream>>>(
          H2, PartE, e_g, e_bn, SS + (size_t)ch * spc * 7 * 512);
    }
    // node L1 (agg GEMM folded): relu(flat@W1f + SS@M + b1 + [m<7168]v6 + av) -> G
    gemmT<4, EP_NL1, 0, 0, 0, 1><<<512, 256, 0, stream>>>(
        flat, 256, 2, SS, 512, 4, nullptr, nullptr, PnW1M, n_b1, v6,
        (round == 0) ? action : nullptr, n_w1,
        nullptr, nullptr, nullptr, G, nullptr, nullptr, 0);
    // node L2 raw + partials: G -> G2
    gemmT<4, EP_RAWP, 0, 0, 1, 1><<<512, 256, 0, stream>>>(
        G, 512, 4, nullptr, 0, 0, nullptr, nullptr, PnW2, n_b2, nullptr,
        nullptr, nullptr, nullptr, nullptr, nullptr, G2, nullptr, PartN, 0);
    // node L3 (+LN on staging, stats from PartN) + residual: G2 -> node, flat +=
    gemmT<2, EP_NL3, 0, 1, 1, 1><<<256, 256, 0, stream>>>(
        G2, 512, 4, nullptr, 0, 0, nullptr, nullptr, PnW3, n_b3, nullptr,
        nullptr, nullptr, PartN, n_g, n_bn, node, flat, nullptr, 0);
  }
}

// Round 21
// 1257.508 us; speedup vs baseline: 2.5071x; 1.0194x over previous
//
#include <hip/hip_runtime.h>
#include <cstddef>

typedef _Float16 f16x8 __attribute__((ext_vector_type(8)));
typedef _Float16 f16x4 __attribute__((ext_vector_type(4)));
typedef float f32x16 __attribute__((ext_vector_type(16)));
typedef unsigned short ushort_t;

#define NSEG 7168
#define NNODE 8192

enum { EP_NONE = 0, EP_BIAS = 1, EP_RAWP = 2, EP_NL1 = 3, EP_NL3 = 4 };

#define PHASE_BARRIER() do { asm volatile("s_waitcnt lgkmcnt(0)" ::: "memory"); \
                             __builtin_amdgcn_s_barrier(); } while (0)

#define RELU8(v) do { _Pragma("unroll") \
  for (int j_ = 0; j_ < 8; ++j_) v[j_] = v[j_] > (_Float16)0 ? v[j_] : (_Float16)0; } while (0)

// ---- prepack W[k][n] fp32 -> 32x32-fragment-native f16 into a pack of NTpack col-tiles
__global__ __launch_bounds__(256)
void prepack(const float* __restrict__ W, ushort_t* __restrict__ P,
             int koff, int kcnt, int Nsrc, int NTpack, int noff) {
  int idx = blockIdx.x * 256 + threadIdx.x;
  if (idx >= kcnt * Nsrc) return;
  int kl = idx / Nsrc, n = idx - kl * Nsrc + noff;
  _Float16 h = (_Float16)W[idx];
  int k = koff + kl;
  size_t o = ((((size_t)(k >> 4)) * NTpack + (n >> 5)) * 64 + ((k >> 3) & 1) * 32 + (n & 31)) * 8 + (k & 7);
  P[o] = __builtin_bit_cast(ushort_t, h);
}

// ---- cast fp32 -> f16 (flat mirror init) ---------------------------------
__global__ __launch_bounds__(256)
void cast16(const float* __restrict__ src, ushort_t* __restrict__ dst, int n) {
  int i = blockIdx.x * 256 + threadIdx.x;
  if (i < n) dst[i] = __builtin_bit_cast(ushort_t, (_Float16)src[i]);
}

// ---- v6[n] = 6 * sum_k e_b3[k] * n_w1[260+k][n] --------------------------
__global__ __launch_bounds__(256)
void v6k(const float* __restrict__ eb3, const float* __restrict__ nw1,
         float* __restrict__ v6) {
  int n = blockIdx.x * 256 + threadIdx.x;
  if (n >= 512) return;
  float a = 0.f;
  for (int k = 0; k < 512; ++k) a += eb3[k] * nw1[(size_t)(260 + k) * 512 + n];
  v6[n] = 6.f * a;
}

// ---- unified 64x128-tile MFMA GEMM, BK=128 phases, 4-deep B prefetch -----
// 256 thr / 4 waves, each wave 32 rows x 64 cols (2 col-tiles).
// LDS exactly 32 KiB; proven (256,4) occupancy config.
template <int NCOLB, int EPI, int EDGE, int LNIN, int X1F16, int OUTF16>
__global__ __launch_bounds__(256, 4)
void gemmT(const void* __restrict__ X1v, int ld1, int nph1,
           const void* __restrict__ X2v, int ld2, int nph2,
           const ushort_t* __restrict__ Sm, const ushort_t* __restrict__ Tm,
           const ushort_t* __restrict__ P,
           const float* __restrict__ bias, const float* __restrict__ bias2,
           const int* __restrict__ action, const float* __restrict__ wact,
           const float* __restrict__ lnpart,
           const float* __restrict__ lng, const float* __restrict__ lnbn,
           void* __restrict__ Yv, float* __restrict__ Yres,
           float* __restrict__ Part, int m0base,
           ushort_t* __restrict__ YresH) {
  constexpr int N = NCOLB * 128;
  constexpr int NT = N / 32;
  const int u = threadIdx.x;
  // bijective XCD-chunk swizzle (m204)
  const int nwg = gridDim.x;
  const int qq = nwg >> 3, r8 = nwg & 7;
  const int xcd = blockIdx.x & 7, inx = blockIdx.x >> 3;
  const int logical = (xcd < r8 ? xcd * (qq + 1) : r8 * (qq + 1) + (xcd - r8) * qq) + inx;
  const int mY = (logical / NCOLB) * 64;
  const int cb = logical - (logical / NCOLB) * NCOLB;
  const int nB = cb * 128;
  const int lane = u & 63, w = u >> 6;
  const int wr = w >> 1, wc = w & 1;
  const int r31 = lane & 31, rt2 = lane >> 5;

  __shared__ ushort_t lA[16384];            // 2 x 8192 f16 = exactly 32 KiB

  // staging: thread (w, lane) stages row=lane, k = w*32..w*32+31 of the phase
  const int kcA = w * 2, kcB = w * 2 + 1;
  const int widx0 = (((rt2 * 8 + kcA) * 2 + 0) * 32 + (r31 ^ ((kcA & 3) << 3))) * 8;
  const int widx1 = (((rt2 * 8 + kcA) * 2 + 1) * 32 + (r31 ^ ((kcA & 3) << 3))) * 8;
  const int widx2 = (((rt2 * 8 + kcB) * 2 + 0) * 32 + (r31 ^ ((kcB & 3) << 3))) * 8;
  const int widx3 = (((rt2 * 8 + kcB) * 2 + 1) * 32 + (r31 ^ ((kcB & 3) << 3))) * 8;

  const ushort_t* sB = nullptr;
  const ushort_t* tB = nullptr;
  const float* x1f = nullptr;
  const ushort_t* x1h = nullptr;
  const ushort_t* x2h = nullptr;
  if (EDGE) {
    // per-thread edge decomposition (staging row = lane)
    int e = m0base + mY + lane;
    int b = e / 42, p = e - b * 42;
    int i = p / 6, tt = p - i * 6;
    int j = tt + (tt >= i ? 1 : 0);
    sB = Sm + (size_t)(b * 7 + i) * 1024 + w * 32;     // [7168][1024] S-half
    tB = Tm + (size_t)(b * 7 + j) * 1024 + w * 32;     // Tm = STb + 512
  } else {
    if (X1F16) x1h = (const ushort_t*)X1v + (size_t)(mY + lane) * ld1 + w * 32;
    else       x1f = (const float*)X1v + (size_t)(mY + lane) * ld1 + w * 32;
    if (nph2 > 0) x2h = (const ushort_t*)X2v + (size_t)(mY + lane) * ld2 + w * 32;
  }
  float mym = 0.f, myr = 0.f;
  if (LNIN) {
    const float* pp = lnpart + (size_t)(mY + lane) * 16;
    float S_ = 0.f, Q_ = 0.f;
    #pragma unroll
    for (int i = 0; i < 8; ++i) { S_ += pp[i]; Q_ += pp[8 + i]; }
    mym = S_ * (1.f / 512.f);
    myr = rsqrtf(Q_ * (1.f / 512.f) - mym * mym + 1e-5f);
  }

  f16x8 xc0, xc1, xc2, xc3;
  auto loadx = [&](int ph) {
    if (EDGE) {
      const ushort_t* sp = sB + ph * 128;
      const ushort_t* tp = tB + ph * 128;
      f16x8 s0 = *(const f16x8*)sp,        t0 = *(const f16x8*)tp;
      f16x8 s1 = *(const f16x8*)(sp + 8),  t1 = *(const f16x8*)(tp + 8);
      f16x8 s2 = *(const f16x8*)(sp + 16), t2 = *(const f16x8*)(tp + 16);
      f16x8 s3 = *(const f16x8*)(sp + 24), t3 = *(const f16x8*)(tp + 24);
      xc0 = s0 + t0; xc1 = s1 + t1; xc2 = s2 + t2; xc3 = s3 + t3;
      RELU8(xc0); RELU8(xc1); RELU8(xc2); RELU8(xc3);
    } else if (!X1F16 && ph < nph1) {
      const float* src = x1f + ph * 128;
      float4 l0 = *(const float4*)(src +  0), h0 = *(const float4*)(src +  4);
      float4 l1 = *(const float4*)(src +  8), h1 = *(const float4*)(src + 12);
      float4 l2 = *(const float4*)(src + 16), h2 = *(const float4*)(src + 20);
      float4 l3 = *(const float4*)(src + 24), h3 = *(const float4*)(src + 28);
#define CVT8(X, lo, hi) do { X[0]=(_Float16)lo.x; X[1]=(_Float16)lo.y; \
      X[2]=(_Float16)lo.z; X[3]=(_Float16)lo.w; X[4]=(_Float16)hi.x; \
      X[5]=(_Float16)hi.y; X[6]=(_Float16)hi.z; X[7]=(_Float16)hi.w; } while (0)
      CVT8(xc0, l0, h0); CVT8(xc1, l1, h1); CVT8(xc2, l2, h2); CVT8(xc3, l3, h3);
#undef CVT8
    } else {
      const ushort_t* src = (ph < nph1) ? x1h + ph * 128 : x2h + (ph - nph1) * 128;
      xc0 = *(const f16x8*)src;
      xc1 = *(const f16x8*)(src + 8);
      xc2 = *(const f16x8*)(src + 16);
      xc3 = *(const f16x8*)(src + 24);
      if (LNIN) {
        const int kb = ph * 128 + w * 32;
#define LN8(X, OFS) do { _Pragma("unroll") for (int j_ = 0; j_ < 8; ++j_) { \
        float xx = (float)X[j_]; \
        xx = fmaxf((xx - mym) * myr * lng[kb + (OFS) + j_] + lnbn[kb + (OFS) + j_], 0.f); \
        X[j_] = (_Float16)xx; } } while (0)
        LN8(xc0, 0); LN8(xc1, 8); LN8(xc2, 16); LN8(xc3, 24);
#undef LN8
      }
    }
  };
  auto cvtwrite = [&](int b) {
    const int base = b * 8192;
    *(f16x8*)&lA[base + widx0] = xc0;
    *(f16x8*)&lA[base + widx1] = xc1;
    *(f16x8*)&lA[base + widx2] = xc2;
    *(f16x8*)&lA[base + widx3] = xc3;
  };

  f32x16 acc0, acc1;
  #pragma unroll
  for (int q = 0; q < 16; ++q) { acc0[q] = 0.f; acc1[q] = 0.f; }

  const int nph = nph1 + nph2;
  const int ntb = (nB >> 5) + wc * 2;
  const int TOT = nph * 8;

#define LOADA(S, A_) do { \
    const int aofs_ = lbase + (((wr * 8 + (S)) * 2 + rt2) * 32 + (r31 ^ (((S) & 3) << 3))) * 8; \
    A_ = *(const f16x8*)&lA[aofs_]; } while (0)

#define LOADB(G_, H0, H1) do { \
    const ushort_t* bp_ = P + (((size_t)(G_) * NT + ntb) * 64 + lane) * 8; \
    H0 = *(const f16x8*)bp_; \
    H1 = *(const f16x8*)(bp_ + 512); } while (0)

#define MFMA2(AH, H0, H1) do { \
    acc0 = __builtin_amdgcn_mfma_f32_32x32x16_f16(AH, H0, acc0, 0, 0, 0); \
    acc1 = __builtin_amdgcn_mfma_f32_32x32x16_f16(AH, H1, acc1, 0, 0, 0); } while (0)

  // prologue: stage phase 0, issue phase-1 loads, prefetch B slots 0..3
  loadx(0);
  cvtwrite(0);
  if (nph > 1) loadx(1);
  PHASE_BARRIER();
  f16x8 b00, b01, b10, b11, b20, b21, b30, b31;
  LOADB(0, b00, b01);
  LOADB(1, b10, b11);
  LOADB(2, b20, b21);
  LOADB(3, b30, b31);

  #pragma unroll 1
  for (int ph = 0; ph < nph; ++ph) {
    if (ph + 1 < nph) {
      cvtwrite((ph + 1) & 1);
      if (ph + 2 < nph) loadx(ph + 2);
    }
    const int lbase = (ph & 1) * 8192;
    const int g0 = ph * 8;
    f16x8 ac, an;
    LOADA(0, ac);
#define STEP(S, BH, BL) do { \
    if ((S) < 7) LOADA((S) + 1, an); \
    f16x8 h0 = BH, h1 = BL; \
    if (g0 + (S) + 4 < TOT) LOADB(g0 + (S) + 4, BH, BL); \
    MFMA2(ac, h0, h1); \
    if ((S) < 7) ac = an; } while (0)
    STEP(0, b00, b01);
    STEP(1, b10, b11);
    STEP(2, b20, b21);
    STEP(3, b30, b31);
    STEP(4, b00, b01);
    STEP(5, b10, b11);
    STEP(6, b20, b21);
    STEP(7, b30, b31);
#undef STEP
    if (ph + 1 < nph) PHASE_BARRIER();
  }

  // ---- epilogue: C/D col = lane&31, row = (q&3) + 8*(q>>2) + 4*(lane>>5) --
  const int col0 = nB + wc * 64 + r31;
  float v[2][16];
  {
    float bc0 = (EPI == EP_NONE) ? 0.f : bias[col0];
    float bc1 = (EPI == EP_NONE) ? 0.f : bias[col0 + 32];
    #pragma unroll
    for (int q = 0; q < 16; ++q) {
      v[0][q] = acc0[q] + bc0;
      v[1][q] = acc1[q] + bc1;
    }
  }

  if (EPI == EP_NL1) {
    #pragma unroll
    for (int q = 0; q < 16; ++q) {
      int m = mY + wr * 32 + (q & 3) + 8 * (q >> 2) + 4 * rt2;
      if (m < NSEG) {
        v[0][q] += bias2[col0];
        v[1][q] += bias2[col0 + 32];
      }
      if (action != nullptr) {
        const float* wrp = wact + (size_t)(256 + action[m >> 3]) * 512;
        v[0][q] += wrp[col0];
        v[1][q] += wrp[col0 + 32];
      }
    }
    #pragma unroll
    for (int ct = 0; ct < 2; ++ct)
      #pragma unroll
      for (int q = 0; q < 16; ++q) v[ct][q] = fmaxf(v[ct][q], 0.f);
  }

  if (EPI == EP_RAWP) {
    float sv[16], qv[16];
    #pragma unroll
    for (int q = 0; q < 16; ++q) {
      sv[q] = v[0][q] + v[1][q];
      qv[q] = v[0][q] * v[0][q] + v[1][q] * v[1][q];
    }
    #pragma unroll
    for (int mm = 1; mm <= 16; mm <<= 1) {
      #pragma unroll
      for (int q = 0; q < 16; ++q) {
        sv[q] += __shfl_xor(sv[q], mm);
        qv[q] += __shfl_xor(qv[q], mm);
      }
    }
    if (r31 == 0) {
      #pragma unroll
      for (int q = 0; q < 16; ++q) {
        int m = mY + wr * 32 + (q & 3) + 8 * (q >> 2) + 4 * rt2;
        Part[(size_t)m * 16 + cb * 2 + wc] = sv[q];
        Part[(size_t)m * 16 + 8 + cb * 2 + wc] = qv[q];
      }
    }
  }

  #pragma unroll
  for (int ct = 0; ct < 2; ++ct) {
    #pragma unroll
    for (int q = 0; q < 16; ++q) {
      int m = mY + wr * 32 + (q & 3) + 8 * (q >> 2) + 4 * rt2;
      float z = v[ct][q];
      if (OUTF16)
        ((ushort_t*)Yv)[(size_t)m * N + col0 + ct * 32] =
            __builtin_bit_cast(ushort_t, (_Float16)z);
      else
        ((float*)Yv)[(size_t)m * N + col0 + ct * 32] = z;
      if (EPI == EP_NL3) {
        float t = Yres[(size_t)m * N + col0 + ct * 32] + z;
        Yres[(size_t)m * N + col0 + ct * 32] = t;
        YresH[(size_t)m * N + col0 + ct * 32] =
            __builtin_bit_cast(ushort_t, (_Float16)t);
      }
    }
  }
#undef LOADA
#undef LOADB
#undef MFMA2
}

// ---- LN(+relu) 6 H2 rows (f16) and sum per segment; stats from Part ------
__global__ __launch_bounds__(256)
void h2_sum_ln(const ushort_t* __restrict__ H2, const float* __restrict__ Part,
               const float* __restrict__ g, const float* __restrict__ bn,
               ushort_t* __restrict__ SS) {
  __shared__ float smu[12], srs[12];
  const int u = threadIdx.x;
  const int g2 = blockIdx.x * 2;
  if (u < 12) {
    const float* pp = Part + ((size_t)g2 * 6 + u) * 16;
    float S = 0.f, Q = 0.f;
    #pragma unroll
    for (int i = 0; i < 8; ++i) { S += pp[i]; Q += pp[8 + i]; }
    float m = S * (1.f / 512.f);
    smu[u] = m;
    srs[u] = rsqrtf(Q * (1.f / 512.f) - m * m + 1e-5f);
  }
  __syncthreads();
  const int ln = g2 + (u >> 7);
  const int lloc = (u >> 7) * 6;
  const int c4 = (u & 127) * 4;
  float4 gv = *(const float4*)(g + c4);
  float4 bv = *(const float4*)(bn + c4);
  float a0 = 0.f, a1 = 0.f, a2 = 0.f, a3 = 0.f;
  #pragma unroll
  for (int r = 0; r < 6; ++r) {
    int row = ln * 6 + r;
    f16x4 y = *(const f16x4*)(H2 + (size_t)row * 512 + c4);
    float m = smu[lloc + r], rs = srs[lloc + r];
    a0 += fmaxf(((float)y[0] - m) * rs * gv.x + bv.x, 0.f);
    a1 += fmaxf(((float)y[1] - m) * rs * gv.y + bv.y, 0.f);
    a2 += fmaxf(((float)y[2] - m) * rs * gv.z + bv.z, 0.f);
    a3 += fmaxf(((float)y[3] - m) * rs * gv.w + bv.w, 0.f);
  }
  f16x4 o;
  o[0] = (_Float16)a0; o[1] = (_Float16)a1; o[2] = (_Float16)a2; o[3] = (_Float16)a3;
  *(f16x4*)(SS + (size_t)ln * 512 + c4) = o;
}

// ---- launcher ------------------------------------------------------------
extern "C" void kernel_launch(void* const* d_in, const int* in_sizes, int n_in,
                              void* d_out, int out_size, void* d_ws, size_t ws_size,
                              hipStream_t stream) {
  (void)in_sizes; (void)n_in; (void)out_size;
  const float* states = (const float*)d_in[0];
  const int* action = (const int*)d_in[1];
  const float* e_w1 = (const float*)d_in[2];
  const float* e_b1 = (const float*)d_in[3];
  const float* e_w2 = (const float*)d_in[4];
  const float* e_b2 = (const float*)d_in[5];
  const float* e_g = (const float*)d_in[6];
  const float* e_bn = (const float*)d_in[7];
  const float* e_w3 = (const float*)d_in[8];
  const float* e_b3 = (const float*)d_in[9];
  const float* n_w1 = (const float*)d_in[10];
  const float* n_b1 = (const float*)d_in[11];
  const float* n_w2 = (const float*)d_in[12];
  const float* n_b2 = (const float*)d_in[13];
  const float* n_g = (const float*)d_in[14];
  const float* n_bn = (const float*)d_in[15];
  const float* n_w3 = (const float*)d_in[16];
  const float* n_b3 = (const float*)d_in[17];

  float* flat = (float*)d_out;                  // [8192][256] fp32 (output)
  float* fp = (float*)d_ws;
  float* Mbuf = fp;  fp += 262144;              // [512][512] fp32
  float* v6 = fp;    fp += 512;
  float* b1ext = fp; fp += 1024;                // [e_b1 | 0]
  float* PartE = fp; fp += 688128;              // [43008][16]
  float* PartN = fp; fp += 131072;              // [8192][16]
  ushort_t* us = (ushort_t*)fp;
  ushort_t* node = us; us += 2097152;           // [8192][256] f16
  ushort_t* flatH = us; us += 2097152;          // [8192][256] f16 mirror of flat
  ushort_t* SS = us;   us += 4194304;           // [8192][512] f16 (tail zeros)
  ushort_t* G = us;    us += 4194304;           // [8192][512] f16
  ushort_t* G2 = us;   us += 4194304;           // [8192][512] f16
  ushort_t* STb = us;  us += 7340032;           // [7168][1024] f16  [S|T]
  ushort_t* PeST = us; us += 524288;            // K512 N1024
  ushort_t* PeW2 = us; us += 262144;
  ushort_t* Ptmp = us; us += 262144;
  ushort_t* PnW1M = us; us += 393216;
  ushort_t* PnW2 = us;  us += 262144;
  ushort_t* PnW3 = us;  us += 131072;
  ushort_t* H2 = us;                            // [43008/nc][512] f16

  const size_t fixedB = (size_t)((char*)H2 - (char*)d_ws);
  int nc = 32;
  for (int cand = 1; cand <= 32; cand <<= 1)
    if (fixedB + (43008ull / cand) * 512ull * 2ull <= ws_size) { nc = cand; break; }
  const int spc = 1024 / nc;
  const int epc = spc * 42;

  // ---- one-time prep ----
  hipMemsetAsync(PeST, 0, 524288 * 2, stream);
  prepack<<<1024, 256, 0, stream>>>(e_w1, PeST, 0, 512, 512, 32, 0);
  prepack<<<512, 256, 0, stream>>>(e_w1 + 262144, PeST, 0, 256, 512, 32, 512);
  prepack<<<1024, 256, 0, stream>>>(e_w2, PeW2, 0, 512, 512, 16, 0);
  prepack<<<1024, 256, 0, stream>>>(n_w1 + 133120, Ptmp, 0, 512, 512, 16, 0);
  prepack<<<512, 256, 0, stream>>>(n_w1, PnW1M, 0, 256, 512, 16, 0);
  prepack<<<1024, 256, 0, stream>>>(n_w2, PnW2, 0, 512, 512, 16, 0);
  prepack<<<512, 256, 0, stream>>>(n_w3, PnW3, 0, 512, 256, 8, 0);
  hipMemcpyAsync(b1ext, e_b1, 512 * 4, hipMemcpyDeviceToDevice, stream);
  hipMemsetAsync(b1ext + 512, 0, 512 * 4, stream);
  // M = e_w3 @ n_w1g (512x512, K=512), fp32 out -> repack
  gemmT<4, EP_NONE, 0, 0, 0, 0><<<32, 256, 0, stream>>>(
      e_w3, 512, 4, nullptr, 0, 0, nullptr, nullptr, Ptmp, nullptr, nullptr,
      nullptr, nullptr, nullptr, nullptr, nullptr, Mbuf, nullptr, nullptr, 0, nullptr);
  prepack<<<1024, 256, 0, stream>>>(Mbuf, PnW1M, 256, 512, 512, 16, 0);
  v6k<<<2, 256, 0, stream>>>(e_b3, n_w1, v6);
  hipMemsetAsync(SS + (size_t)NSEG * 512, 0, (size_t)(NNODE - NSEG) * 512 * 2, stream);
  hipMemcpyAsync(flat, states, (size_t)NNODE * 256 * 4, hipMemcpyDeviceToDevice, stream);
  cast16<<<8192, 256, 0, stream>>>(states, flatH, NNODE * 256);

  for (int round = 0; round < 8; ++round) {
    // [S|T] = [flatH|node] @ PeST + [b1|0]  (7168 rows, N=1024, f16 out)
    if (round == 0)
      gemmT<8, EP_BIAS, 0, 0, 1, 1><<<896, 256, 0, stream>>>(
          flatH, 256, 2, nullptr, 0, 0, nullptr, nullptr, PeST, b1ext, nullptr,
          nullptr, nullptr, nullptr, nullptr, nullptr, STb, nullptr, nullptr, 0, nullptr);
    else
      gemmT<8, EP_BIAS, 0, 0, 1, 1><<<896, 256, 0, stream>>>(
          flatH, 256, 2, node, 256, 2, nullptr, nullptr, PeST, b1ext, nullptr,
          nullptr, nullptr, nullptr, nullptr, nullptr, STb, nullptr, nullptr, 0, nullptr);
    // edge layer 2 (gather S[row]+T[col], relu) raw f16 + fp32 partials; LN+sum6
    for (int ch = 0; ch < nc; ++ch) {
      gemmT<4, EP_RAWP, 1, 0, 0, 1><<<(epc / 64) * 4, 256, 0, stream>>>(
          nullptr, 0, 4, nullptr, 0, 0, STb, STb + 512, PeW2, e_b2, nullptr,
          nullptr, nullptr, nullptr, nullptr, nullptr,
          H2, nullptr, PartE, ch * epc, nullptr);
      h2_sum_ln<<<(spc * 7) / 2, 256, 0, stream>>>(
          H2, PartE, e_g, e_bn, SS + (size_t)ch * spc * 7 * 512);
    }
    // node L1 (agg GEMM folded): relu(flatH@W1f + SS@M + b1 + [m<7168]v6 + av) -> G
    gemmT<4, EP_NL1, 0, 0, 1, 1><<<512, 256, 0, stream>>>(
        flatH, 256, 2, SS, 512, 4, nullptr, nullptr, PnW1M, n_b1, v6,
        (round == 0) ? action : nullptr, n_w1,
        nullptr, nullptr, nullptr, G, nullptr, nullptr, 0, nullptr);
    // node L2 raw + partials: G -> G2
    gemmT<4, EP_RAWP, 0, 0, 1, 1><<<512, 256, 0, stream>>>(
        G, 512, 4, nullptr, 0, 0, nullptr, nullptr, PnW2, n_b2, nullptr,
        nullptr, nullptr, nullptr, nullptr, nullptr, G2, nullptr, PartN, 0, nullptr);
    // node L3 (+LN on staging, stats from PartN) + residual: G2 -> node, flat+=, flatH=
    gemmT<2, EP_NL3, 0, 1, 1, 1><<<256, 256, 0, stream>>>(
        G2, 512, 4, nullptr, 0, 0, nullptr, nullptr, PnW3, n_b3, nullptr,
        nullptr, nullptr, PartN, n_g, n_bn, node, flat, nullptr, 0, flatH);
  }
}

// Round 22
// 1256.675 us; speedup vs baseline: 2.5087x; 1.0007x over previous
//
#include <hip/hip_runtime.h>
#include <cstddef>

typedef _Float16 f16x8 __attribute__((ext_vector_type(8)));
typedef _Float16 f16x4 __attribute__((ext_vector_type(4)));
typedef float f32x16 __attribute__((ext_vector_type(16)));
typedef unsigned short ushort_t;

#define NSEG 7168
#define NNODE 8192

enum { EP_NONE = 0, EP_BIAS = 1, EP_RAWP = 2, EP_NL1 = 3, EP_NL3 = 4 };

#define PHASE_BARRIER() do { asm volatile("s_waitcnt lgkmcnt(0)" ::: "memory"); \
                             __builtin_amdgcn_s_barrier(); } while (0)

#define RELU8(v) do { _Pragma("unroll") \
  for (int j_ = 0; j_ < 8; ++j_) v[j_] = v[j_] > (_Float16)0 ? v[j_] : (_Float16)0; } while (0)

// ---- prepack W[k][n] fp32 -> 32x32-fragment-native f16 into a pack of NTpack col-tiles
__global__ __launch_bounds__(256)
void prepack(const float* __restrict__ W, ushort_t* __restrict__ P,
             int koff, int kcnt, int Nsrc, int NTpack, int noff) {
  int idx = blockIdx.x * 256 + threadIdx.x;
  if (idx >= kcnt * Nsrc) return;
  int kl = idx / Nsrc, n = idx - kl * Nsrc + noff;
  _Float16 h = (_Float16)W[idx];
  int k = koff + kl;
  size_t o = ((((size_t)(k >> 4)) * NTpack + (n >> 5)) * 64 + ((k >> 3) & 1) * 32 + (n & 31)) * 8 + (k & 7);
  P[o] = __builtin_bit_cast(ushort_t, h);
}

// ---- cast fp32 -> f16 (flat mirror init) ---------------------------------
__global__ __launch_bounds__(256)
void cast16(const float* __restrict__ src, ushort_t* __restrict__ dst, int n) {
  int i = blockIdx.x * 256 + threadIdx.x;
  if (i < n) dst[i] = __builtin_bit_cast(ushort_t, (_Float16)src[i]);
}

// ---- v6[n] = 6 * sum_k e_b3[k] * n_w1[260+k][n] --------------------------
__global__ __launch_bounds__(256)
void v6k(const float* __restrict__ eb3, const float* __restrict__ nw1,
         float* __restrict__ v6) {
  int n = blockIdx.x * 256 + threadIdx.x;
  if (n >= 512) return;
  float a = 0.f;
  for (int k = 0; k < 512; ++k) a += eb3[k] * nw1[(size_t)(260 + k) * 512 + n];
  v6[n] = 6.f * a;
}

// ---- unified 64x128-tile MFMA GEMM, BK=128 phases, 4-deep B prefetch -----
// 256 thr / 4 waves, each wave 32 rows x 64 cols (2 col-tiles).
// LDS exactly 32 KiB; proven (256,4) occupancy config.
template <int NCOLB, int EPI, int EDGE, int LNIN, int X1F16, int OUTF16>
__global__ __launch_bounds__(256, 4)
void gemmT(const void* __restrict__ X1v, int ld1, int nph1,
           const void* __restrict__ X2v, int ld2, int nph2,
           const ushort_t* __restrict__ Sm, const ushort_t* __restrict__ Tm,
           const ushort_t* __restrict__ P,
           const float* __restrict__ bias, const float* __restrict__ bias2,
           const int* __restrict__ action, const float* __restrict__ wact,
           const float* __restrict__ lnpart,
           const float* __restrict__ lng, const float* __restrict__ lnbn,
           void* __restrict__ Yv, float* __restrict__ Yres,
           float* __restrict__ Part, int m0base,
           ushort_t* __restrict__ YresH) {
  constexpr int N = NCOLB * 128;
  constexpr int NT = N / 32;
  const int u = threadIdx.x;
  // bijective XCD-chunk swizzle (m204)
  const int nwg = gridDim.x;
  const int qq = nwg >> 3, r8 = nwg & 7;
  const int xcd = blockIdx.x & 7, inx = blockIdx.x >> 3;
  const int logical = (xcd < r8 ? xcd * (qq + 1) : r8 * (qq + 1) + (xcd - r8) * qq) + inx;
  const int mY = (logical / NCOLB) * 64;
  const int cb = logical - (logical / NCOLB) * NCOLB;
  const int nB = cb * 128;
  const int lane = u & 63, w = u >> 6;
  const int wr = w >> 1, wc = w & 1;
  const int r31 = lane & 31, rt2 = lane >> 5;

  __shared__ ushort_t lA[16384];            // 2 x 8192 f16 = exactly 32 KiB

  // staging: thread (w, lane) stages row=lane, k = w*32..w*32+31 of the phase
  const int kcA = w * 2, kcB = w * 2 + 1;
  const int widx0 = (((rt2 * 8 + kcA) * 2 + 0) * 32 + (r31 ^ ((kcA & 3) << 3))) * 8;
  const int widx1 = (((rt2 * 8 + kcA) * 2 + 1) * 32 + (r31 ^ ((kcA & 3) << 3))) * 8;
  const int widx2 = (((rt2 * 8 + kcB) * 2 + 0) * 32 + (r31 ^ ((kcB & 3) << 3))) * 8;
  const int widx3 = (((rt2 * 8 + kcB) * 2 + 1) * 32 + (r31 ^ ((kcB & 3) << 3))) * 8;

  const ushort_t* sB = nullptr;
  const ushort_t* tB = nullptr;
  const float* x1f = nullptr;
  const ushort_t* x1h = nullptr;
  const ushort_t* x2h = nullptr;
  if (EDGE) {
    // per-thread edge decomposition (staging row = lane)
    int e = m0base + mY + lane;
    int b = e / 42, p = e - b * 42;
    int i = p / 6, tt = p - i * 6;
    int j = tt + (tt >= i ? 1 : 0);
    sB = Sm + (size_t)(b * 7 + i) * 1024 + w * 32;     // [7168][1024] S-half
    tB = Tm + (size_t)(b * 7 + j) * 1024 + w * 32;     // Tm = STb + 512
  } else {
    if (X1F16) x1h = (const ushort_t*)X1v + (size_t)(mY + lane) * ld1 + w * 32;
    else       x1f = (const float*)X1v + (size_t)(mY + lane) * ld1 + w * 32;
    if (nph2 > 0) x2h = (const ushort_t*)X2v + (size_t)(mY + lane) * ld2 + w * 32;
  }
  float mym = 0.f, myr = 0.f;
  if (LNIN) {
    const float* pp = lnpart + (size_t)(mY + lane) * 16;
    float S_ = 0.f, Q_ = 0.f;
    #pragma unroll
    for (int i = 0; i < 8; ++i) { S_ += pp[i]; Q_ += pp[8 + i]; }
    mym = S_ * (1.f / 512.f);
    myr = rsqrtf(Q_ * (1.f / 512.f) - mym * mym + 1e-5f);
  }

  f16x8 xc0, xc1, xc2, xc3;
  auto loadx = [&](int ph) {
    if (EDGE) {
      const ushort_t* sp = sB + ph * 128;
      const ushort_t* tp = tB + ph * 128;
      f16x8 s0 = *(const f16x8*)sp,        t0 = *(const f16x8*)tp;
      f16x8 s1 = *(const f16x8*)(sp + 8),  t1 = *(const f16x8*)(tp + 8);
      f16x8 s2 = *(const f16x8*)(sp + 16), t2 = *(const f16x8*)(tp + 16);
      f16x8 s3 = *(const f16x8*)(sp + 24), t3 = *(const f16x8*)(tp + 24);
      xc0 = s0 + t0; xc1 = s1 + t1; xc2 = s2 + t2; xc3 = s3 + t3;
      RELU8(xc0); RELU8(xc1); RELU8(xc2); RELU8(xc3);
    } else if (!X1F16 && ph < nph1) {
      const float* src = x1f + ph * 128;
      float4 l0 = *(const float4*)(src +  0), h0 = *(const float4*)(src +  4);
      float4 l1 = *(const float4*)(src +  8), h1 = *(const float4*)(src + 12);
      float4 l2 = *(const float4*)(src + 16), h2 = *(const float4*)(src + 20);
      float4 l3 = *(const float4*)(src + 24), h3 = *(const float4*)(src + 28);
#define CVT8(X, lo, hi) do { X[0]=(_Float16)lo.x; X[1]=(_Float16)lo.y; \
      X[2]=(_Float16)lo.z; X[3]=(_Float16)lo.w; X[4]=(_Float16)hi.x; \
      X[5]=(_Float16)hi.y; X[6]=(_Float16)hi.z; X[7]=(_Float16)hi.w; } while (0)
      CVT8(xc0, l0, h0); CVT8(xc1, l1, h1); CVT8(xc2, l2, h2); CVT8(xc3, l3, h3);
#undef CVT8
    } else {
      const ushort_t* src = (ph < nph1) ? x1h + ph * 128 : x2h + (ph - nph1) * 128;
      xc0 = *(const f16x8*)src;
      xc1 = *(const f16x8*)(src + 8);
      xc2 = *(const f16x8*)(src + 16);
      xc3 = *(const f16x8*)(src + 24);
      if (LNIN) {
        const int kb = ph * 128 + w * 32;
#define LN8(X, OFS) do { _Pragma("unroll") for (int j_ = 0; j_ < 8; ++j_) { \
        float xx = (float)X[j_]; \
        xx = fmaxf((xx - mym) * myr * lng[kb + (OFS) + j_] + lnbn[kb + (OFS) + j_], 0.f); \
        X[j_] = (_Float16)xx; } } while (0)
        LN8(xc0, 0); LN8(xc1, 8); LN8(xc2, 16); LN8(xc3, 24);
#undef LN8
      }
    }
  };
  auto cvtwrite = [&](int b) {
    const int base = b * 8192;
    *(f16x8*)&lA[base + widx0] = xc0;
    *(f16x8*)&lA[base + widx1] = xc1;
    *(f16x8*)&lA[base + widx2] = xc2;
    *(f16x8*)&lA[base + widx3] = xc3;
  };

  f32x16 acc0, acc1;
  #pragma unroll
  for (int q = 0; q < 16; ++q) { acc0[q] = 0.f; acc1[q] = 0.f; }

  const int nph = nph1 + nph2;
  const int ntb = (nB >> 5) + wc * 2;
  const int TOT = nph * 8;

#define LOADA(S, A_) do { \
    const int aofs_ = lbase + (((wr * 8 + (S)) * 2 + rt2) * 32 + (r31 ^ (((S) & 3) << 3))) * 8; \
    A_ = *(const f16x8*)&lA[aofs_]; } while (0)

#define LOADB(G_, H0, H1) do { \
    const ushort_t* bp_ = P + (((size_t)(G_) * NT + ntb) * 64 + lane) * 8; \
    H0 = *(const f16x8*)bp_; \
    H1 = *(const f16x8*)(bp_ + 512); } while (0)

#define MFMA2(AH, H0, H1) do { \
    acc0 = __builtin_amdgcn_mfma_f32_32x32x16_f16(AH, H0, acc0, 0, 0, 0); \
    acc1 = __builtin_amdgcn_mfma_f32_32x32x16_f16(AH, H1, acc1, 0, 0, 0); } while (0)

  // prologue: stage phase 0, issue phase-1 loads, prefetch B slots 0..3
  loadx(0);
  cvtwrite(0);
  if (nph > 1) loadx(1);
  PHASE_BARRIER();
  f16x8 b00, b01, b10, b11, b20, b21, b30, b31;
  LOADB(0, b00, b01);
  LOADB(1, b10, b11);
  LOADB(2, b20, b21);
  LOADB(3, b30, b31);

  #pragma unroll 1
  for (int ph = 0; ph < nph; ++ph) {
    if (ph + 1 < nph) {
      cvtwrite((ph + 1) & 1);
      if (ph + 2 < nph) loadx(ph + 2);
    }
    const int lbase = (ph & 1) * 8192;
    const int g0 = ph * 8;
    f16x8 ac, an;
    LOADA(0, ac);
#define STEP(S, BH, BL) do { \
    if ((S) < 7) LOADA((S) + 1, an); \
    f16x8 h0 = BH, h1 = BL; \
    if (g0 + (S) + 4 < TOT) LOADB(g0 + (S) + 4, BH, BL); \
    MFMA2(ac, h0, h1); \
    if ((S) < 7) ac = an; } while (0)
    STEP(0, b00, b01);
    STEP(1, b10, b11);
    STEP(2, b20, b21);
    STEP(3, b30, b31);
    STEP(4, b00, b01);
    STEP(5, b10, b11);
    STEP(6, b20, b21);
    STEP(7, b30, b31);
#undef STEP
    if (ph + 1 < nph) PHASE_BARRIER();
  }

  // ---- epilogue: C/D col = lane&31, row = (q&3) + 8*(q>>2) + 4*(lane>>5) --
  const int col0 = nB + wc * 64 + r31;
  float v[2][16];
  {
    float bc0 = (EPI == EP_NONE) ? 0.f : bias[col0];
    float bc1 = (EPI == EP_NONE) ? 0.f : bias[col0 + 32];
    #pragma unroll
    for (int q = 0; q < 16; ++q) {
      v[0][q] = acc0[q] + bc0;
      v[1][q] = acc1[q] + bc1;
    }
  }

  if (EPI == EP_NL1) {
    #pragma unroll
    for (int q = 0; q < 16; ++q) {
      int m = mY + wr * 32 + (q & 3) + 8 * (q >> 2) + 4 * rt2;
      if (m < NSEG) {
        v[0][q] += bias2[col0];
        v[1][q] += bias2[col0 + 32];
      }
      if (action != nullptr) {
        const float* wrp = wact + (size_t)(256 + action[m >> 3]) * 512;
        v[0][q] += wrp[col0];
        v[1][q] += wrp[col0 + 32];
      }
    }
    #pragma unroll
    for (int ct = 0; ct < 2; ++ct)
      #pragma unroll
      for (int q = 0; q < 16; ++q) v[ct][q] = fmaxf(v[ct][q], 0.f);
  }

  if (EPI == EP_RAWP) {
    float sv[16], qv[16];
    #pragma unroll
    for (int q = 0; q < 16; ++q) {
      sv[q] = v[0][q] + v[1][q];
      qv[q] = v[0][q] * v[0][q] + v[1][q] * v[1][q];
    }
    #pragma unroll
    for (int mm = 1; mm <= 16; mm <<= 1) {
      #pragma unroll
      for (int q = 0; q < 16; ++q) {
        sv[q] += __shfl_xor(sv[q], mm);
        qv[q] += __shfl_xor(qv[q], mm);
      }
    }
    if (r31 == 0) {
      #pragma unroll
      for (int q = 0; q < 16; ++q) {
        int m = mY + wr * 32 + (q & 3) + 8 * (q >> 2) + 4 * rt2;
        Part[(size_t)m * 16 + cb * 2 + wc] = sv[q];
        Part[(size_t)m * 16 + 8 + cb * 2 + wc] = qv[q];
      }
    }
  }

  #pragma unroll
  for (int ct = 0; ct < 2; ++ct) {
    #pragma unroll
    for (int q = 0; q < 16; ++q) {
      int m = mY + wr * 32 + (q & 3) + 8 * (q >> 2) + 4 * rt2;
      float z = v[ct][q];
      if (OUTF16)
        ((ushort_t*)Yv)[(size_t)m * N + col0 + ct * 32] =
            __builtin_bit_cast(ushort_t, (_Float16)z);
      else
        ((float*)Yv)[(size_t)m * N + col0 + ct * 32] = z;
      if (EPI == EP_NL3) {
        float t = Yres[(size_t)m * N + col0 + ct * 32] + z;
        Yres[(size_t)m * N + col0 + ct * 32] = t;
        YresH[(size_t)m * N + col0 + ct * 32] =
            __builtin_bit_cast(ushort_t, (_Float16)t);
      }
    }
  }
#undef LOADA
#undef LOADB
#undef MFMA2
}

// ---- LN(+relu) 6 H2 rows (f16) and sum per segment; stats from Part ------
__global__ __launch_bounds__(256)
void h2_sum_ln(const ushort_t* __restrict__ H2, const float* __restrict__ Part,
               const float* __restrict__ g, const float* __restrict__ bn,
               ushort_t* __restrict__ SS) {
  __shared__ float smu[12], srs[12];
  const int u = threadIdx.x;
  const int g2 = blockIdx.x * 2;
  if (u < 12) {
    const float* pp = Part + ((size_t)g2 * 6 + u) * 16;
    float S = 0.f, Q = 0.f;
    #pragma unroll
    for (int i = 0; i < 8; ++i) { S += pp[i]; Q += pp[8 + i]; }
    float m = S * (1.f / 512.f);
    smu[u] = m;
    srs[u] = rsqrtf(Q * (1.f / 512.f) - m * m + 1e-5f);
  }
  __syncthreads();
  const int ln = g2 + (u >> 7);
  const int lloc = (u >> 7) * 6;
  const int c4 = (u & 127) * 4;
  float4 gv = *(const float4*)(g + c4);
  float4 bv = *(const float4*)(bn + c4);
  float a0 = 0.f, a1 = 0.f, a2 = 0.f, a3 = 0.f;
  #pragma unroll
  for (int r = 0; r < 6; ++r) {
    int row = ln * 6 + r;
    f16x4 y = *(const f16x4*)(H2 + (size_t)row * 512 + c4);
    float m = smu[lloc + r], rs = srs[lloc + r];
    a0 += fmaxf(((float)y[0] - m) * rs * gv.x + bv.x, 0.f);
    a1 += fmaxf(((float)y[1] - m) * rs * gv.y + bv.y, 0.f);
    a2 += fmaxf(((float)y[2] - m) * rs * gv.z + bv.z, 0.f);
    a3 += fmaxf(((float)y[3] - m) * rs * gv.w + bv.w, 0.f);
  }
  f16x4 o;
  o[0] = (_Float16)a0; o[1] = (_Float16)a1; o[2] = (_Float16)a2; o[3] = (_Float16)a3;
  *(f16x4*)(SS + (size_t)ln * 512 + c4) = o;
}

// ---- launcher ------------------------------------------------------------
extern "C" void kernel_launch(void* const* d_in, const int* in_sizes, int n_in,
                              void* d_out, int out_size, void* d_ws, size_t ws_size,
                              hipStream_t stream) {
  (void)in_sizes; (void)n_in; (void)out_size;
  const float* states = (const float*)d_in[0];
  const int* action = (const int*)d_in[1];
  const float* e_w1 = (const float*)d_in[2];
  const float* e_b1 = (const float*)d_in[3];
  const float* e_w2 = (const float*)d_in[4];
  const float* e_b2 = (const float*)d_in[5];
  const float* e_g = (const float*)d_in[6];
  const float* e_bn = (const float*)d_in[7];
  const float* e_w3 = (const float*)d_in[8];
  const float* e_b3 = (const float*)d_in[9];
  const float* n_w1 = (const float*)d_in[10];
  const float* n_b1 = (const float*)d_in[11];
  const float* n_w2 = (const float*)d_in[12];
  const float* n_b2 = (const float*)d_in[13];
  const float* n_g = (const float*)d_in[14];
  const float* n_bn = (const float*)d_in[15];
  const float* n_w3 = (const float*)d_in[16];
  const float* n_b3 = (const float*)d_in[17];

  float* flat = (float*)d_out;                  // [8192][256] fp32 (output)
  float* fp = (float*)d_ws;
  float* Mbuf = fp;  fp += 262144;              // [512][512] fp32
  float* v6 = fp;    fp += 512;
  float* b1ext = fp; fp += 1024;                // [e_b1 | 0]
  float* PartE = fp; fp += 688128;              // [43008][16]
  float* PartN = fp; fp += 131072;              // [8192][16]
  ushort_t* us = (ushort_t*)fp;
  ushort_t* node = us; us += 2097152;           // [8192][256] f16
  ushort_t* flatH = us; us += 2097152;          // [8192][256] f16 mirror of flat
  ushort_t* SS = us;   us += 4194304;           // [8192][512] f16 (tail zeros)
  ushort_t* G = us;    us += 4194304;           // [8192][512] f16
  ushort_t* G2 = us;   us += 4194304;           // [8192][512] f16
  ushort_t* STb = us;  us += 7340032;           // [7168][1024] f16  [S|T]
  ushort_t* PeST = us; us += 524288;            // K512 N1024
  ushort_t* PeW2 = us; us += 262144;
  ushort_t* Ptmp = us; us += 262144;
  ushort_t* PnW1M = us; us += 393216;
  ushort_t* PnW2 = us;  us += 262144;
  ushort_t* PnW3 = us;  us += 131072;
  ushort_t* H2 = us;                            // [43008/nc][512] f16

  const size_t fixedB = (size_t)((char*)H2 - (char*)d_ws);
  int nc = 32;
  for (int cand = 1; cand <= 32; cand <<= 1)
    if (fixedB + (43008ull / cand) * 512ull * 2ull <= ws_size) { nc = cand; break; }
  const int spc = 1024 / nc;
  const int epc = spc * 42;

  // ---- one-time prep ----
  hipMemsetAsync(PeST, 0, 524288 * 2, stream);
  prepack<<<1024, 256, 0, stream>>>(e_w1, PeST, 0, 512, 512, 32, 0);
  prepack<<<512, 256, 0, stream>>>(e_w1 + 262144, PeST, 0, 256, 512, 32, 512);
  prepack<<<1024, 256, 0, stream>>>(e_w2, PeW2, 0, 512, 512, 16, 0);
  prepack<<<1024, 256, 0, stream>>>(n_w1 + 133120, Ptmp, 0, 512, 512, 16, 0);
  prepack<<<512, 256, 0, stream>>>(n_w1, PnW1M, 0, 256, 512, 16, 0);
  prepack<<<1024, 256, 0, stream>>>(n_w2, PnW2, 0, 512, 512, 16, 0);
  prepack<<<512, 256, 0, stream>>>(n_w3, PnW3, 0, 512, 256, 8, 0);
  hipMemcpyAsync(b1ext, e_b1, 512 * 4, hipMemcpyDeviceToDevice, stream);
  hipMemsetAsync(b1ext + 512, 0, 512 * 4, stream);
  // M = e_w3 @ n_w1g (512x512, K=512), fp32 out -> repack
  gemmT<4, EP_NONE, 0, 0, 0, 0><<<32, 256, 0, stream>>>(
      e_w3, 512, 4, nullptr, 0, 0, nullptr, nullptr, Ptmp, nullptr, nullptr,
      nullptr, nullptr, nullptr, nullptr, nullptr, Mbuf, nullptr, nullptr, 0, nullptr);
  prepack<<<1024, 256, 0, stream>>>(Mbuf, PnW1M, 256, 512, 512, 16, 0);
  v6k<<<2, 256, 0, stream>>>(e_b3, n_w1, v6);
  hipMemsetAsync(SS + (size_t)NSEG * 512, 0, (size_t)(NNODE - NSEG) * 512 * 2, stream);
  hipMemcpyAsync(flat, states, (size_t)NNODE * 256 * 4, hipMemcpyDeviceToDevice, stream);
  cast16<<<8192, 256, 0, stream>>>(states, flatH, NNODE * 256);

  for (int round = 0; round < 8; ++round) {
    // [S|T] = [flatH|node] @ PeST + [b1|0]  (7168 rows, N=1024, f16 out)
    if (round == 0)
      gemmT<8, EP_BIAS, 0, 0, 1, 1><<<896, 256, 0, stream>>>(
          flatH, 256, 2, nullptr, 0, 0, nullptr, nullptr, PeST, b1ext, nullptr,
          nullptr, nullptr, nullptr, nullptr, nullptr, STb, nullptr, nullptr, 0, nullptr);
    else
      gemmT<8, EP_BIAS, 0, 0, 1, 1><<<896, 256, 0, stream>>>(
          flatH, 256, 2, node, 256, 2, nullptr, nullptr, PeST, b1ext, nullptr,
          nullptr, nullptr, nullptr, nullptr, nullptr, STb, nullptr, nullptr, 0, nullptr);
    // edge layer 2 (gather S[row]+T[col], relu) raw f16 + fp32 partials; LN+sum6
    for (int ch = 0; ch < nc; ++ch) {
      gemmT<4, EP_RAWP, 1, 0, 0, 1><<<(epc / 64) * 4, 256, 0, stream>>>(
          nullptr, 0, 4, nullptr, 0, 0, STb, STb + 512, PeW2, e_b2, nullptr,
          nullptr, nullptr, nullptr, nullptr, nullptr,
          H2, nullptr, PartE, ch * epc, nullptr);
      h2_sum_ln<<<(spc * 7) / 2, 256, 0, stream>>>(
          H2, PartE, e_g, e_bn, SS + (size_t)ch * spc * 7 * 512);
    }
    // node L1 (agg GEMM folded): relu(flatH@W1f + SS@M + b1 + [m<7168]v6 + av) -> G
    gemmT<4, EP_NL1, 0, 0, 1, 1><<<512, 256, 0, stream>>>(
        flatH, 256, 2, SS, 512, 4, nullptr, nullptr, PnW1M, n_b1, v6,
        (round == 0) ? action : nullptr, n_w1,
        nullptr, nullptr, nullptr, G, nullptr, nullptr, 0, nullptr);
    // node L2 raw + partials: G -> G2
    gemmT<4, EP_RAWP, 0, 0, 1, 1><<<512, 256, 0, stream>>>(
        G, 512, 4, nullptr, 0, 0, nullptr, nullptr, PnW2, n_b2, nullptr,
        nullptr, nullptr, nullptr, nullptr, nullptr, G2, nullptr, PartN, 0, nullptr);
    // node L3 (+LN on staging, stats from PartN) + residual: G2 -> node, flat+=, flatH=
    gemmT<2, EP_NL3, 0, 1, 1, 1><<<256, 256, 0, stream>>>(
        G2, 512, 4, nullptr, 0, 0, nullptr, nullptr, PnW3, n_b3, nullptr,
        nullptr, nullptr, PartN, n_g, n_bn, node, flat, nullptr, 0, flatH);
  }
}